// Round 11
// baseline (523.093 us; speedup 1.0000x reference)
//
#include <hip/hip_runtime.h>
#include <hip/hip_bf16.h>
#include <math.h>

// Problem constants (fixed by the reference)
#define NB    4096      // number of anchors  (B / GROUP)
#define BB    20480     // total rows of inputs = columns of sim
#define DD    512       // feature dim
#define EPc    0.1f
#define BETAc  10.0f
#define ALPHAc 2.0f
#define LMDAc  1.0f
// LSE shift: masked args BETA*(s-1) span ~[-700, 1400].
#define SHIFT  1400.0

typedef __attribute__((ext_vector_type(8))) short bf16x8;   // 8 bf16 (4 VGPRs)
typedef __attribute__((ext_vector_type(4))) float f32x4;    // MFMA accumulator
typedef unsigned int u32;

// global_load_lds, 16B per lane. LDS dest is wave-uniform base + lane*16 (m104);
// global src is per-lane (pre-swizzled there, rule 21).
#define GLOAD16(gp, lp) \
    __builtin_amdgcn_global_load_lds((const __attribute__((address_space(1))) u32*)(gp), \
                                     (__attribute__((address_space(3))) u32*)(lp), 16, 0, 0)

// ---- monotone float <-> uint key (for atomicMax on float incl. negatives) ----
__device__ __forceinline__ unsigned fenc(float x) {
    unsigned b = __float_as_uint(x);
    return (b & 0x80000000u) ? ~b : (b | 0x80000000u);
}
__device__ __forceinline__ float fdec(unsigned k) {
    unsigned b = (k & 0x80000000u) ? (k ^ 0x80000000u) : ~k;
    return __uint_as_float(b);
}

// ---- f32 pair -> packed bf16 hi / lo words ----
__device__ __forceinline__ void split2(float a, float b, u32* h, u32* l) {
    __hip_bfloat16 ha = __float2bfloat16(a);
    __hip_bfloat16 hb = __float2bfloat16(b);
    unsigned short ba, bb;
    __builtin_memcpy(&ba, &ha, 2); __builtin_memcpy(&bb, &hb, 2);
    float fa = __uint_as_float((u32)ba << 16);
    float fb = __uint_as_float((u32)bb << 16);
    __hip_bfloat16 la = __float2bfloat16(a - fa);
    __hip_bfloat16 lb = __float2bfloat16(b - fb);
    unsigned short ca, cb;
    __builtin_memcpy(&ca, &la, 2); __builtin_memcpy(&cb, &lb, 2);
    *h = (u32)ba | ((u32)bb << 16);
    *l = (u32)ca | ((u32)cb << 16);
}

// ============================================================================
// Kernel 0: split inputs into Hi/Lo bf16 arrays (row-major [BB][DD], packed).
// ============================================================================
__global__ __launch_bounds__(256) void split_kernel(const float* __restrict__ inp,
        u32* __restrict__ hi, u32* __restrict__ lo)
{
    const size_t e = ((size_t)blockIdx.x * 256 + threadIdx.x) * 8;
    float4 x0 = *(const float4*)(inp + e);
    float4 x1 = *(const float4*)(inp + e + 4);
    u32 h[4], l[4];
    split2(x0.x, x0.y, &h[0], &l[0]);
    split2(x0.z, x0.w, &h[1], &l[1]);
    split2(x1.x, x1.y, &h[2], &l[2]);
    split2(x1.z, x1.w, &h[3], &l[3]);
    *(uint4*)(hi + e / 2) = make_uint4(h[0], h[1], h[2], h[3]);
    *(uint4*)(lo + e / 2) = make_uint4(l[0], l[1], l[2], l[3]);
}

// ============================================================================
// Kernel 1: pos[i][g-1] = f_i . inputs[5i+g] (exact f32); posmin[i] = min
// ============================================================================
__global__ __launch_bounds__(256) void pos_kernel(const float* __restrict__ inp,
        float* __restrict__ pos, float* __restrict__ posmin)
{
    const int wid  = threadIdx.x >> 6;
    const int lane = threadIdx.x & 63;
    const int i = blockIdx.x * 4 + wid;
    const float* f = inp + (size_t)(5 * i) * DD + lane * 8;
    float4 fa = *(const float4*)(f);
    float4 fb = *(const float4*)(f + 4);
    float pmin = INFINITY;
    #pragma unroll
    for (int g = 1; g < 5; ++g) {
        const float* x = inp + (size_t)(5 * i + g) * DD + lane * 8;
        float4 xa = *(const float4*)(x);
        float4 xb = *(const float4*)(x + 4);
        float s = fa.x*xa.x + fa.y*xa.y + fa.z*xa.z + fa.w*xa.w
                + fb.x*xb.x + fb.y*xb.y + fb.z*xb.z + fb.w*xb.w;
        #pragma unroll
        for (int m = 1; m < 64; m <<= 1) s += __shfl_xor(s, m, 64);
        if (lane == 0) pos[i * 4 + (g - 1)] = s;
        pmin = fminf(pmin, s);
    }
    if (lane == 0) posmin[i] = pmin;
}

// ============================================================================
// Per-row LSE/max/count fold + atomics for one accumulator row-register.
// ============================================================================
__device__ __forceinline__ void row_epilogue(int i, int c0, int wc, int l15,
        float s0, float s1, float s2, float s3,
        const float* __restrict__ posmin, unsigned* __restrict__ negkey,
        double* __restrict__ msum, unsigned* __restrict__ cntn)
{
    const float th = posmin[i] - EPc;     // strict >
    float vmax = -INFINITY;
    float lM   = -INFINITY;
    float lS   = 0.f;
    int   vcnt = 0;
    float sv[4] = {s0, s1, s2, s3};
    float args[4]; bool msk[4];
    #pragma unroll
    for (int fc = 0; fc < 4; ++fc) {
        const int c = c0 + wc + fc * 16 + l15;
        const float s = sv[fc];
        const bool nonown = ((c / 5) != i);
        msk[fc]  = nonown && (s > th);
        args[fc] = BETAc * (s - LMDAc);
        if (nonown)  vmax = fmaxf(vmax, s);
        if (msk[fc]) { vcnt += 1; lM = fmaxf(lM, args[fc]); }
    }
    #pragma unroll
    for (int fc = 0; fc < 4; ++fc)
        if (msk[fc]) lS += __expf(args[fc] - lM);
    #pragma unroll
    for (int m = 1; m < 16; m <<= 1) {
        vmax  = fmaxf(vmax, __shfl_xor(vmax, m, 64));
        vcnt += __shfl_xor(vcnt, m, 64);
        float oM = __shfl_xor(lM, m, 64);
        float oS = __shfl_xor(lS, m, 64);
        if (oS != 0.f) {
            if (lS == 0.f)      { lM = oM; lS = oS; }
            else if (lM >= oM)  { lS += oS * __expf(oM - lM); }
            else                { lS = oS + lS * __expf(lM - oM); lM = oM; }
        }
    }
    if (l15 == 0) {
        atomicMax(&negkey[i], fenc(vmax));
        atomicAdd(&cntn[i], (unsigned)vcnt);
        if (lS > 0.f) {
            double e = (double)lM - SHIFT;
            if (e > 690.0) e = 690.0;
            double Dv = exp(e) * (double)lS;
            if (!(Dv < 1e300)) Dv = 1e300;    // also catches nan
            atomicAdd(&msum[i], Dv);
        }
    }
}

// ============================================================================
// Kernel 2 (fast path): STANDARD bf16 GEMM over virtual K=1536:
//   sim = Ah.Bh + Al.Bh + Ah.Bl  ==  A'.B'^T,  A'=[Ah|Al|Ah], B'=[Bh|Bh|Bl]
// realized by selecting the global staging source per K-step s (p = s>>4):
//   A from {hi,lo,hi}[p], B from {hi,hi,lo}[p]  (wave-uniform SGPR select).
// 128x128 tile, BK=32, 4 waves (64x64 each, one MFMA per acc per step —
// no dependent chains), LDS 2 x 16 KB dbuf, counted-vmcnt pipeline
// (r9-verified skeleton, vmcnt(4) steady state, raw s_barrier, tail peeled).
// LDS micro-layout: 64B rows, chunk swizzle c^((row>>1)&3) on global-src
// (write side, rule 21) and ds_read (read side) — verified 0-conflict.
// ============================================================================
__global__ __launch_bounds__(256) void sim_mfma7(const u32* __restrict__ hi,
        const u32* __restrict__ lo, const float* __restrict__ posmin,
        unsigned* __restrict__ negkey, double* __restrict__ msum,
        unsigned* __restrict__ cntn)
{
    __shared__ u32 As0[2048], Bs0[2048];   // 8 KB each
    __shared__ u32 As1[2048], Bs1[2048];

    const int t    = threadIdx.x;
    const int bj   = blockIdx.x % (BB / 128);   // 160 col tiles
    const int bi   = blockIdx.x / (BB / 128);   // 32 row tiles
    const int i0   = bi * 128;
    const int c0   = bj * 128;
    const int lane = t & 63;
    const int w    = t >> 6;
    const int wr   = (w >> 1) * 64;
    const int wc   = (w & 1) * 64;
    const int l15  = lane & 15;
    const int l4   = lane >> 4;

    // ---- staging: wave w covers rows [w*32, w*32+32) of A and B tiles ----
    const int srow = w * 32 + (lane >> 2);      // +16 for the second GLOAD
    const int sc   = (lane & 3) ^ ((srow >> 1) & 3);  // logical chunk fetched
    // row byte bases in the [BB][512]-bf16 arrays (1024 B row stride)
    const size_t rbA0 = (size_t)(5 * (i0 + srow))      * 1024 + sc * 16;
    const size_t rbA1 = (size_t)(5 * (i0 + srow + 16)) * 1024 + sc * 16;
    const size_t rbB0 = (size_t)(c0 + srow)      * 1024 + sc * 16;
    const size_t rbB1 = (size_t)(c0 + srow + 16) * 1024 + sc * 16;
    const int dL0 = (w * 32) * 16;              // u32 index, wave-uniform
    const int dL1 = (w * 32 + 16) * 16;

// K-step s in [0,48): p = s>>4 selects source arrays; kk = (s&15)*64 bytes.
#define STAGE(AS, BS, s) do {                                            \
    const int p_ = (s) >> 4;                                             \
    const size_t kk_ = (size_t)((s) & 15) * 64;                          \
    const char* bA_ = (const char*)(p_ == 1 ? lo : hi);                  \
    const char* bB_ = (const char*)(p_ == 2 ? lo : hi);                  \
    GLOAD16(bA_ + rbA0 + kk_, (AS) + dL0);                               \
    GLOAD16(bA_ + rbA1 + kk_, (AS) + dL1);                               \
    GLOAD16(bB_ + rbB0 + kk_, (BS) + dL0);                               \
    GLOAD16(bB_ + rbB1 + kk_, (BS) + dL1);                               \
} while (0)

    f32x4 acc[4][4];
    #pragma unroll
    for (int a = 0; a < 4; ++a)
        #pragma unroll
        for (int b = 0; b < 4; ++b) acc[a][b] = (f32x4)0.f;

    // swizzled LDS byte offsets for fragment reads
    int aoff[4], boff[4];
    #pragma unroll
    for (int f = 0; f < 4; ++f) {
        const int row = wr + f * 16 + l15;
        const int col = wc + f * 16 + l15;
        aoff[f] = row * 64 + ((l4 ^ ((row >> 1) & 3)) * 16);
        boff[f] = col * 64 + ((l4 ^ ((col >> 1) & 3)) * 16);
    }

#define COMPUTE(AS, BS) do {                                             \
    bf16x8 bv[4];                                                        \
    _Pragma("unroll")                                                    \
    for (int fc = 0; fc < 4; ++fc)                                       \
        bv[fc] = *(const bf16x8*)((const char*)(BS) + boff[fc]);         \
    _Pragma("unroll")                                                    \
    for (int fr = 0; fr < 4; ++fr) {                                     \
        bf16x8 av = *(const bf16x8*)((const char*)(AS) + aoff[fr]);      \
        _Pragma("unroll")                                                \
        for (int fc = 0; fc < 4; ++fc)                                   \
            acc[fr][fc] = __builtin_amdgcn_mfma_f32_16x16x32_bf16(av, bv[fc], acc[fr][fc], 0, 0, 0); \
    }                                                                    \
} while (0)

#define VMCNT4  asm volatile("s_waitcnt vmcnt(4)" ::: "memory")
#define VMCNT0  asm volatile("s_waitcnt vmcnt(0)" ::: "memory")
#define MFENCE  asm volatile("" ::: "memory")
#define BARRIER __builtin_amdgcn_s_barrier()

    // prologue: both buffers in flight (8 outstanding loads)
    STAGE(As0, Bs0, 0);
    STAGE(As1, Bs1, 1);

    // steady state: s = 0..45 (23 iterations x 2 phases); vmcnt(4) waits the
    // OLDEST 4 loads (current buffer) while the next buffer's 4 keep flying.
    for (int it = 0; it < 23; ++it) {
        VMCNT4; BARRIER; MFENCE;
        COMPUTE(As0, Bs0);
        BARRIER; MFENCE;                      // all waves done reading buf0
        STAGE(As0, Bs0, 2 * it + 2);
        VMCNT4; BARRIER; MFENCE;
        COMPUTE(As1, Bs1);
        BARRIER; MFENCE;                      // all waves done reading buf1
        STAGE(As1, Bs1, 2 * it + 3);
    }
    // tail: s=46 (buf0; 4 younger loads [s=47] still outstanding -> vmcnt(4))
    VMCNT4; BARRIER; MFENCE;
    COMPUTE(As0, Bs0);
    // tail: s=47 (buf1; nothing younger -> vmcnt(0))
    VMCNT0; BARRIER; MFENCE;
    COMPUTE(As1, Bs1);

#undef STAGE
#undef COMPUTE
#undef VMCNT4
#undef VMCNT0
#undef MFENCE
#undef BARRIER

    // ---- fused epilogue. C/D layout: col = lane&15, row = (lane>>4)*4 + reg
    #pragma unroll
    for (int fr = 0; fr < 4; ++fr) {
        #pragma unroll
        for (int reg = 0; reg < 4; ++reg) {
            const int i = i0 + wr + fr * 16 + l4 * 4 + reg;
            row_epilogue(i, c0, wc, l15,
                         acc[fr][0][reg], acc[fr][1][reg],
                         acc[fr][2][reg], acc[fr][3][reg],
                         posmin, negkey, msum, cntn);
        }
    }
}

// ============================================================================
// Kernel 2 (fallback, ws too small): in-kernel cvt, known-good from round 4.
// ============================================================================
__device__ __forceinline__ void cvt8(const float* __restrict__ src,
                                     uint4* __restrict__ dhi, uint4* __restrict__ dlo)
{
    float4 x0 = *(const float4*)(src);
    float4 x1 = *(const float4*)(src + 4);
    float xs[8] = {x0.x, x0.y, x0.z, x0.w, x1.x, x1.y, x1.z, x1.w};
    u32 h[4], l[4];
    #pragma unroll
    for (int p = 0; p < 4; ++p) split2(xs[2*p], xs[2*p+1], &h[p], &l[p]);
    *dhi = make_uint4(h[0], h[1], h[2], h[3]);
    *dlo = make_uint4(l[0], l[1], l[2], l[3]);
}

__global__ __launch_bounds__(256) void sim_mfma(const float* __restrict__ inp,
        const float* __restrict__ posmin, unsigned* __restrict__ negkey,
        double* __restrict__ msum, unsigned* __restrict__ cntn)
{
    __shared__ uint4 AsHi[128][4];
    __shared__ uint4 AsLo[128][4];
    __shared__ uint4 BsHi[128][4];
    __shared__ uint4 BsLo[128][4];

    const int t    = threadIdx.x;
    const int bj   = blockIdx.x % (BB / 128);
    const int bi   = blockIdx.x / (BB / 128);
    const int i0   = bi * 128;
    const int c0   = bj * 128;
    const int lane = t & 63;
    const int w    = t >> 6;
    const int wr   = (w >> 1) * 64;
    const int wc   = (w & 1) * 64;
    const int l15  = lane & 15;
    const int l4   = lane >> 4;

    f32x4 acc[4][4];
    #pragma unroll
    for (int a = 0; a < 4; ++a)
        #pragma unroll
        for (int b = 0; b < 4; ++b) acc[a][b] = (f32x4)0.f;

    const int r0  = t >> 2;
    const int ch0 = t & 3;

    for (int kb = 0; kb < DD; kb += 32) {
        __syncthreads();
        #pragma unroll
        for (int half = 0; half < 2; ++half) {
            const int row = r0 + half * 64;
            const int cs  = ch0 ^ ((row >> 2) & 3);
            cvt8(inp + (size_t)(5 * (i0 + row)) * DD + kb + ch0 * 8,
                 &AsHi[row][cs], &AsLo[row][cs]);
            cvt8(inp + (size_t)(c0 + row) * DD + kb + ch0 * 8,
                 &BsHi[row][cs], &BsLo[row][cs]);
        }
        __syncthreads();

        bf16x8 bh[4], bl[4];
        #pragma unroll
        for (int fc = 0; fc < 4; ++fc) {
            const int col = wc + fc * 16 + l15;
            const int cs  = l4 ^ ((col >> 2) & 3);
            bh[fc] = *(const bf16x8*)&BsHi[col][cs];
            bl[fc] = *(const bf16x8*)&BsLo[col][cs];
        }
        #pragma unroll
        for (int fr = 0; fr < 4; ++fr) {
            const int row = wr + fr * 16 + l15;
            const int cs  = l4 ^ ((row >> 2) & 3);
            bf16x8 ah = *(const bf16x8*)&AsHi[row][cs];
            bf16x8 al = *(const bf16x8*)&AsLo[row][cs];
            #pragma unroll
            for (int fc = 0; fc < 4; ++fc) {
                acc[fr][fc] = __builtin_amdgcn_mfma_f32_16x16x32_bf16(ah, bh[fc], acc[fr][fc], 0, 0, 0);
                acc[fr][fc] = __builtin_amdgcn_mfma_f32_16x16x32_bf16(ah, bl[fc], acc[fr][fc], 0, 0, 0);
                acc[fr][fc] = __builtin_amdgcn_mfma_f32_16x16x32_bf16(al, bh[fc], acc[fr][fc], 0, 0, 0);
            }
        }
    }

    #pragma unroll
    for (int fr = 0; fr < 4; ++fr) {
        #pragma unroll
        for (int reg = 0; reg < 4; ++reg) {
            const int i = i0 + wr + fr * 16 + l4 * 4 + reg;
            row_epilogue(i, c0, wc, l15,
                         acc[fr][0][reg], acc[fr][1][reg],
                         acc[fr][2][reg], acc[fr][3][reg],
                         posmin, negkey, msum, cntn);
        }
    }
}

// ============================================================================
// Kernel 3: finalize.
// ============================================================================
__global__ __launch_bounds__(1024) void fin_kernel(const float* __restrict__ pos,
        const unsigned* __restrict__ negkey, const double* __restrict__ msum,
        const unsigned* __restrict__ cntn, float* __restrict__ out)
{
    const int t = threadIdx.x;
    double lossAcc = 0.0;
    int pAcc = 0, nAcc = 0;
    for (int r = t; r < NB; r += 1024) {
        const float negmax = fdec(negkey[r]);
        const float thr = negmax + EPc;       // strict <
        float Mp = -INFINITY; int pc = 0;
        float pa[4]; bool pm[4];
        #pragma unroll
        for (int g = 0; g < 4; ++g) {
            const float p = pos[r * 4 + g];
            pa[g] = -ALPHAc * (p - LMDAc);
            pm[g] = (p < thr);
            if (pm[g]) { pc += 1; Mp = fmaxf(Mp, pa[g]); }
        }
        double lp = 0.0;
        if (pc > 0) {
            float sp = 0.f;
            #pragma unroll
            for (int g = 0; g < 4; ++g)
                if (pm[g]) sp += __expf(pa[g] - Mp);
            double a = (double)Mp + log((double)sp);
            lp = (a > 30.0 ? a : log1p(exp(a))) / (double)ALPHAc;
        }
        double ln = 0.0;
        double Dsum = msum[r];
        if (Dsum > 0.0) {
            double a = SHIFT + log(Dsum);
            ln = (a > 30.0 ? a : log1p(exp(a))) / (double)BETAc;
        }
        double contrib = lp + ln;
        if (!(contrib < 1e30)) contrib = 1e30;
        lossAcc += contrib;
        pAcc += pc;
        nAcc += (int)cntn[r];
    }
    __shared__ double sl[1024];
    __shared__ int    sp_[1024];
    __shared__ int    sn_[1024];
    sl[t] = lossAcc; sp_[t] = pAcc; sn_[t] = nAcc;
    __syncthreads();
    for (int s = 512; s > 0; s >>= 1) {
        if (t < s) { sl[t] += sl[t + s]; sp_[t] += sp_[t + s]; sn_[t] += sn_[t + s]; }
        __syncthreads();
    }
    if (t == 0) {
        double loss = sl[0] / 4096.0;
        if (!(loss < 1e30)) loss = 1e30;
        out[0] = (float)loss;
        out[1] = (float)sp_[0] / 16384.0f;
        out[2] = (float)sn_[0] / 83865600.0f;
    }
}

// ============================================================================
extern "C" void kernel_launch(void* const* d_in, const int* in_sizes, int n_in,
                              void* d_out, int out_size, void* d_ws, size_t ws_size,
                              hipStream_t stream)
{
    (void)in_sizes; (void)n_in; (void)out_size;
    const float* inp = (const float*)d_in[0];   // (20480, 512) f32; targets unused
    char* ws = (char*)d_ws;
    // ws layout (bytes):
    //   [0      , 65536 )  pos      : 4096*4 f32
    //   [65536  , 81920 )  posmin   : 4096 f32
    //   [81920  , 98304 )  negkey   : 4096 u32
    //   [98304  , 131072)  msum     : 4096 f64
    //   [131072 , 147456)  cntn     : 4096 u32
    //   [147456 , +21.0MB)  Hi bf16 [BB][DD]
    //   [ ...   , +21.0MB)  Lo bf16 [BB][DD]
    float*    pos    = (float*)   (ws);
    float*    posmin = (float*)   (ws + 65536);
    unsigned* negkey = (unsigned*)(ws + 81920);
    double*   msum   = (double*)  (ws + 98304);
    unsigned* cntn   = (unsigned*)(ws + 131072);
    u32*      hi     = (u32*)     (ws + 147456);
    u32*      lo     = (u32*)     (ws + 147456 + (size_t)BB * DD * 2);
    float*    out    = (float*)d_out;
    const size_t need = 147456 + (size_t)BB * DD * 4;   // 42.1 MB

    hipMemsetAsync(ws + 81920, 0, 65536, stream);
    hipLaunchKernelGGL(pos_kernel, dim3(NB / 4), dim3(256), 0, stream, inp, pos, posmin);

    if (ws_size >= need) {
        hipLaunchKernelGGL(split_kernel, dim3(BB * DD / (256 * 8)), dim3(256), 0, stream,
                           inp, hi, lo);
        hipLaunchKernelGGL(sim_mfma7, dim3((NB / 128) * (BB / 128)), dim3(256), 0, stream,
                           hi, lo, posmin, negkey, msum, cntn);
    } else {
        hipLaunchKernelGGL(sim_mfma, dim3((NB / 128) * (BB / 128)), dim3(256), 0, stream,
                           inp, posmin, negkey, msum, cntn);
    }
    hipLaunchKernelGGL(fin_kernel, dim3(1), dim3(1024), 0, stream, pos, negkey, msum, cntn, out);
}

// Round 12
// 515.051 us; speedup vs baseline: 1.0156x; 1.0156x over previous
//
#include <hip/hip_runtime.h>
#include <hip/hip_bf16.h>
#include <math.h>

// Problem constants (fixed by the reference)
#define NB    4096      // number of anchors  (B / GROUP)
#define BB    20480     // total rows of inputs = columns of sim
#define DD    512       // feature dim
#define EPc    0.1f
#define BETAc  10.0f
#define ALPHAc 2.0f
#define LMDAc  1.0f
// LSE shift: masked args BETA*(s-1) span ~[-700, 1400].
#define SHIFT  1400.0

typedef __attribute__((ext_vector_type(8))) short bf16x8;   // 8 bf16 (4 VGPRs)
typedef __attribute__((ext_vector_type(4))) float f32x4;    // MFMA accumulator
typedef unsigned int u32;

// global_load_lds, 16B per lane. LDS dest is wave-uniform base + lane*16 (m104);
// global src is per-lane (pre-swizzled there, rule 21).
#define GLOAD16(gp, lp) \
    __builtin_amdgcn_global_load_lds((const __attribute__((address_space(1))) u32*)(gp), \
                                     (__attribute__((address_space(3))) u32*)(lp), 16, 0, 0)

// ---- monotone float <-> uint key (for atomicMax on float incl. negatives) ----
__device__ __forceinline__ unsigned fenc(float x) {
    unsigned b = __float_as_uint(x);
    return (b & 0x80000000u) ? ~b : (b | 0x80000000u);
}
__device__ __forceinline__ float fdec(unsigned k) {
    unsigned b = (k & 0x80000000u) ? (k ^ 0x80000000u) : ~k;
    return __uint_as_float(b);
}

// ---- f32 pair -> packed bf16 hi / lo words ----
__device__ __forceinline__ void split2(float a, float b, u32* h, u32* l) {
    __hip_bfloat16 ha = __float2bfloat16(a);
    __hip_bfloat16 hb = __float2bfloat16(b);
    unsigned short ba, bb;
    __builtin_memcpy(&ba, &ha, 2); __builtin_memcpy(&bb, &hb, 2);
    float fa = __uint_as_float((u32)ba << 16);
    float fb = __uint_as_float((u32)bb << 16);
    __hip_bfloat16 la = __float2bfloat16(a - fa);
    __hip_bfloat16 lb = __float2bfloat16(b - fb);
    unsigned short ca, cb;
    __builtin_memcpy(&ca, &la, 2); __builtin_memcpy(&cb, &lb, 2);
    *h = (u32)ba | ((u32)bb << 16);
    *l = (u32)ca | ((u32)cb << 16);
}

// ============================================================================
// Kernel 0: split inputs into Hi/Lo bf16 arrays (row-major [BB][DD], packed).
// ============================================================================
__global__ __launch_bounds__(256) void split_kernel(const float* __restrict__ inp,
        u32* __restrict__ hi, u32* __restrict__ lo)
{
    const size_t e = ((size_t)blockIdx.x * 256 + threadIdx.x) * 8;
    float4 x0 = *(const float4*)(inp + e);
    float4 x1 = *(const float4*)(inp + e + 4);
    u32 h[4], l[4];
    split2(x0.x, x0.y, &h[0], &l[0]);
    split2(x0.z, x0.w, &h[1], &l[1]);
    split2(x1.x, x1.y, &h[2], &l[2]);
    split2(x1.z, x1.w, &h[3], &l[3]);
    *(uint4*)(hi + e / 2) = make_uint4(h[0], h[1], h[2], h[3]);
    *(uint4*)(lo + e / 2) = make_uint4(l[0], l[1], l[2], l[3]);
}

// ============================================================================
// Kernel 1: pos[i][g-1] = f_i . inputs[5i+g] (exact f32); posmin[i] = min
// ============================================================================
__global__ __launch_bounds__(256) void pos_kernel(const float* __restrict__ inp,
        float* __restrict__ pos, float* __restrict__ posmin)
{
    const int wid  = threadIdx.x >> 6;
    const int lane = threadIdx.x & 63;
    const int i = blockIdx.x * 4 + wid;
    const float* f = inp + (size_t)(5 * i) * DD + lane * 8;
    float4 fa = *(const float4*)(f);
    float4 fb = *(const float4*)(f + 4);
    float pmin = INFINITY;
    #pragma unroll
    for (int g = 1; g < 5; ++g) {
        const float* x = inp + (size_t)(5 * i + g) * DD + lane * 8;
        float4 xa = *(const float4*)(x);
        float4 xb = *(const float4*)(x + 4);
        float s = fa.x*xa.x + fa.y*xa.y + fa.z*xa.z + fa.w*xa.w
                + fb.x*xb.x + fb.y*xb.y + fb.z*xb.z + fb.w*xb.w;
        #pragma unroll
        for (int m = 1; m < 64; m <<= 1) s += __shfl_xor(s, m, 64);
        if (lane == 0) pos[i * 4 + (g - 1)] = s;
        pmin = fminf(pmin, s);
    }
    if (lane == 0) posmin[i] = pmin;
}

// ============================================================================
// Per-row LSE/max/count fold + atomics for one accumulator row-register.
// ============================================================================
__device__ __forceinline__ void row_epilogue(int i, int c0, int wc, int l15,
        float s0, float s1, float s2, float s3,
        const float* __restrict__ posmin, unsigned* __restrict__ negkey,
        double* __restrict__ msum, unsigned* __restrict__ cntn)
{
    const float th = posmin[i] - EPc;     // strict >
    float vmax = -INFINITY;
    float lM   = -INFINITY;
    float lS   = 0.f;
    int   vcnt = 0;
    float sv[4] = {s0, s1, s2, s3};
    float args[4]; bool msk[4];
    #pragma unroll
    for (int fc = 0; fc < 4; ++fc) {
        const int c = c0 + wc + fc * 16 + l15;
        const float s = sv[fc];
        const bool nonown = ((c / 5) != i);
        msk[fc]  = nonown && (s > th);
        args[fc] = BETAc * (s - LMDAc);
        if (nonown)  vmax = fmaxf(vmax, s);
        if (msk[fc]) { vcnt += 1; lM = fmaxf(lM, args[fc]); }
    }
    #pragma unroll
    for (int fc = 0; fc < 4; ++fc)
        if (msk[fc]) lS += __expf(args[fc] - lM);
    #pragma unroll
    for (int m = 1; m < 16; m <<= 1) {
        vmax  = fmaxf(vmax, __shfl_xor(vmax, m, 64));
        vcnt += __shfl_xor(vcnt, m, 64);
        float oM = __shfl_xor(lM, m, 64);
        float oS = __shfl_xor(lS, m, 64);
        if (oS != 0.f) {
            if (lS == 0.f)      { lM = oM; lS = oS; }
            else if (lM >= oM)  { lS += oS * __expf(oM - lM); }
            else                { lS = oS + lS * __expf(lM - oM); lM = oM; }
        }
    }
    if (l15 == 0) {
        atomicMax(&negkey[i], fenc(vmax));
        atomicAdd(&cntn[i], (unsigned)vcnt);
        if (lS > 0.f) {
            double e = (double)lM - SHIFT;
            if (e > 690.0) e = 690.0;
            double Dv = exp(e) * (double)lS;
            if (!(Dv < 1e300)) Dv = 1e300;    // also catches nan
            atomicAdd(&msum[i], Dv);
        }
    }
}

// ============================================================================
// Kernel 2 (fast path): virtual-K (1536) bf16 GEMM, 256x256 tile, 8 waves
// (2Mx4N, wave tile 128x64), BK=32, RING OF 4 LDS K-tile buffers (128 KB),
// per-quadrant sub-phases (8 MFMA + barrier pair each), counted vmcnt:
//   - tile T computes from buf T%4; tile T+3 stages into buf (T+3)%4
//     (the buffer of tile T-1, protected by barrier ordering) -> 3-tile lead.
//   - 4 gloads/thread/tile; steady vmcnt(8) == tiles T+2,T+3 in flight;
//     vmcnt precedes the barrier so all threads' loads are visible.
// LDS micro-layout (verified 0-conflict r6-r11): 64B rows, chunk swizzle
// c^((row>>1)&3) on global source (write, rule 21) and ds_read (read).
// ============================================================================
__global__ __launch_bounds__(512, 2) void sim_mfma8(const u32* __restrict__ hi,
        const u32* __restrict__ lo, const float* __restrict__ posmin,
        unsigned* __restrict__ negkey, double* __restrict__ msum,
        unsigned* __restrict__ cntn)
{
    __shared__ u32 A0[4096], B0[4096], A1[4096], B1[4096];
    __shared__ u32 A2[4096], B2[4096], A3[4096], B3[4096];   // 8 x 16 KB = 128 KB

    const int t    = threadIdx.x;
    // bijective XCD swizzle (nwg = 1280, 1280 % 8 == 0)
    const int bid  = blockIdx.x;
    const int swzb = (bid & 7) * 160 + (bid >> 3);
    const int bi   = swzb / (BB / 256);
    const int bj   = swzb % (BB / 256);
    const int i0   = bi * 256;
    const int c0   = bj * 256;
    const int lane = t & 63;
    const int w    = t >> 6;                    // wave 0..7
    const int wr   = (w >> 2) * 128;            // 0 or 128
    const int wc   = (w & 3) * 64;              // 0/64/128/192
    const int l15  = lane & 15;
    const int l4   = lane >> 4;

    // ---- staging geometry: thread t owns row r=t>>2, chunk slot cp=t&3 ----
    const int r  = t >> 2;                      // 0..127 (+128 for slot 1)
    const int cp = t & 3;
    const int sc = cp ^ ((r >> 1) & 3);         // logical chunk fetched
    // ((r+128)>>1)&3 == (r>>1)&3, so sc valid for both halves.
    const size_t gA0 = (size_t)(5 * (i0 + r))       * 1024 + sc * 16;
    const size_t gA1 = (size_t)(5 * (i0 + r + 128)) * 1024 + sc * 16;
    const size_t gB0 = (size_t)(c0 + r)        * 1024 + sc * 16;
    const size_t gB1 = (size_t)(c0 + r + 128)  * 1024 + sc * 16;
    const int dW0 = w * 256;                    // wave-uniform LDS dst (u32)
    const int dW1 = 2048 + w * 256;

// per-half-tile stage ops; T is the K-tile index (0..47), p=T>>4 picks array
#define STG_A0(AB, T) do { const char* b_ = (const char*)((((T) >> 4) == 1) ? lo : hi); \
    GLOAD16(b_ + gA0 + (size_t)((T) & 15) * 64, (AB) + dW0); } while (0)
#define STG_A1(AB, T) do { const char* b_ = (const char*)((((T) >> 4) == 1) ? lo : hi); \
    GLOAD16(b_ + gA1 + (size_t)((T) & 15) * 64, (AB) + dW1); } while (0)
#define STG_B0(BB_, T) do { const char* b_ = (const char*)((((T) >> 4) == 2) ? lo : hi); \
    GLOAD16(b_ + gB0 + (size_t)((T) & 15) * 64, (BB_) + dW0); } while (0)
#define STG_B1(BB_, T) do { const char* b_ = (const char*)((((T) >> 4) == 2) ? lo : hi); \
    GLOAD16(b_ + gB1 + (size_t)((T) & 15) * 64, (BB_) + dW1); } while (0)

    f32x4 acc[8][4];
    #pragma unroll
    for (int a = 0; a < 8; ++a)
        #pragma unroll
        for (int b = 0; b < 4; ++b) acc[a][b] = (f32x4)0.f;

    // swizzled LDS byte offsets for fragment reads
    int aoff[8], boff[4];
    #pragma unroll
    for (int f = 0; f < 8; ++f) {
        const int row = wr + f * 16 + l15;
        aoff[f] = row * 64 + ((l4 ^ ((row >> 1) & 3)) * 16);
    }
    #pragma unroll
    for (int f = 0; f < 4; ++f) {
        const int col = wc + f * 16 + l15;
        boff[f] = col * 64 + ((l4 ^ ((col >> 1) & 3)) * 16);
    }

    bf16x8 av[8], bv[4];

#define RD(BUF, OFF) (*(const bf16x8*)((const char*)(BUF) + (OFF)))
#define MM(FR, FC) do {                                                      \
    _Pragma("unroll")                                                        \
    for (int fr_ = (FR); fr_ < (FR) + 4; ++fr_) {                            \
        _Pragma("unroll")                                                    \
        for (int fc_ = (FC); fc_ < (FC) + 2; ++fc_)                          \
            acc[fr_][fc_] = __builtin_amdgcn_mfma_f32_16x16x32_bf16(         \
                av[fr_], bv[fc_], acc[fr_][fc_], 0, 0, 0);                   \
    } } while (0)

#define MFENCE  asm volatile("" ::: "memory")
#define BARM    do { MFENCE; __builtin_amdgcn_s_barrier(); MFENCE; } while (0)
#define SP1     __builtin_amdgcn_s_setprio(1)
#define SP0     __builtin_amdgcn_s_setprio(0)
#define VM8     asm volatile("s_waitcnt vmcnt(8)" ::: "memory")
#define VM4     asm volatile("s_waitcnt vmcnt(4)" ::: "memory")
#define VM0     asm volatile("s_waitcnt vmcnt(0)" ::: "memory")

// One K-tile: 4 sub-phases (quadrants), each {reads | 1 stage-load | barrier |
// prio-wrapped 8 MFMA | barrier}. VMEND (for tile T+1) sits before the final
// barrier so every thread's wait precedes the sync (write-visibility).
#define TILE(AB, BB_, SA, SB, T, DOSTG, VMEND) do {                          \
    av[0] = RD(AB, aoff[0]); av[1] = RD(AB, aoff[1]);                        \
    av[2] = RD(AB, aoff[2]); av[3] = RD(AB, aoff[3]);                        \
    bv[0] = RD(BB_, boff[0]); bv[1] = RD(BB_, boff[1]);                      \
    if (DOSTG) STG_A0(SA, (T) + 3);                                          \
    BARM; SP1; MM(0, 0); SP0; BARM;                                          \
    bv[2] = RD(BB_, boff[2]); bv[3] = RD(BB_, boff[3]);                      \
    if (DOSTG) STG_A1(SA, (T) + 3);                                          \
    BARM; SP1; MM(0, 2); SP0; BARM;                                          \
    av[4] = RD(AB, aoff[4]); av[5] = RD(AB, aoff[5]);                        \
    av[6] = RD(AB, aoff[6]); av[7] = RD(AB, aoff[7]);                        \
    if (DOSTG) STG_B0(SB, (T) + 3);                                          \
    BARM; SP1; MM(4, 0); SP0; BARM;                                          \
    if (DOSTG) STG_B1(SB, (T) + 3);                                          \
    BARM; SP1; MM(4, 2); SP0; VMEND; BARM;                                   \
} while (0)

    // prologue: stage K-tiles 0,1,2 (12 loads); wait tile 0 (vmcnt(8)); sync.
    STG_A0(A0, 0); STG_A1(A0, 0); STG_B0(B0, 0); STG_B1(B0, 0);
    STG_A0(A1, 1); STG_A1(A1, 1); STG_B0(B1, 1); STG_B1(B1, 1);
    STG_A0(A2, 2); STG_A1(A2, 2); STG_B0(B2, 2); STG_B1(B2, 2);
    VM8; BARM;

    // main: T = 0..43 (ring: buf T%4 computed, buf (T+3)%4 restaged)
    int T = 0;
    for (int u = 0; u < 11; ++u) {
        TILE(A0, B0, A3, B3, T, 1, VM8); T++;
        TILE(A1, B1, A0, B0, T, 1, VM8); T++;
        TILE(A2, B2, A1, B1, T, 1, VM8); T++;
        TILE(A3, B3, A2, B2, T, 1, VM8); T++;
    }
    // tail: T = 44 (stages 47), 45..47 (no stage), vmcnt ledger 8/8/4/0
    TILE(A0, B0, A3, B3, 44, 1, VM8);
    TILE(A1, B1, A0, B0, 45, 0, VM4);
    TILE(A2, B2, A0, B0, 46, 0, VM0);
    TILE(A3, B3, A0, B0, 47, 0, MFENCE);

#undef TILE
#undef STG_A0
#undef STG_A1
#undef STG_B0
#undef STG_B1
#undef RD
#undef MM

    // ---- fused epilogue. C/D layout: col = lane&15, row = (lane>>4)*4 + reg
    #pragma unroll
    for (int fr = 0; fr < 8; ++fr) {
        #pragma unroll
        for (int reg = 0; reg < 4; ++reg) {
            const int i = i0 + wr + fr * 16 + l4 * 4 + reg;
            row_epilogue(i, c0, wc, l15,
                         acc[fr][0][reg], acc[fr][1][reg],
                         acc[fr][2][reg], acc[fr][3][reg],
                         posmin, negkey, msum, cntn);
        }
    }
}

// ============================================================================
// Kernel 2 (fallback, ws too small): in-kernel cvt, known-good from round 4.
// ============================================================================
__device__ __forceinline__ void cvt8(const float* __restrict__ src,
                                     uint4* __restrict__ dhi, uint4* __restrict__ dlo)
{
    float4 x0 = *(const float4*)(src);
    float4 x1 = *(const float4*)(src + 4);
    float xs[8] = {x0.x, x0.y, x0.z, x0.w, x1.x, x1.y, x1.z, x1.w};
    u32 h[4], l[4];
    #pragma unroll
    for (int p = 0; p < 4; ++p) split2(xs[2*p], xs[2*p+1], &h[p], &l[p]);
    *dhi = make_uint4(h[0], h[1], h[2], h[3]);
    *dlo = make_uint4(l[0], l[1], l[2], l[3]);
}

__global__ __launch_bounds__(256) void sim_mfma(const float* __restrict__ inp,
        const float* __restrict__ posmin, unsigned* __restrict__ negkey,
        double* __restrict__ msum, unsigned* __restrict__ cntn)
{
    __shared__ uint4 AsHi[128][4];
    __shared__ uint4 AsLo[128][4];
    __shared__ uint4 BsHi[128][4];
    __shared__ uint4 BsLo[128][4];

    const int t    = threadIdx.x;
    const int bj   = blockIdx.x % (BB / 128);
    const int bi   = blockIdx.x / (BB / 128);
    const int i0   = bi * 128;
    const int c0   = bj * 128;
    const int lane = t & 63;
    const int w    = t >> 6;
    const int wr   = (w >> 1) * 64;
    const int wc   = (w & 1) * 64;
    const int l15  = lane & 15;
    const int l4   = lane >> 4;

    f32x4 acc[4][4];
    #pragma unroll
    for (int a = 0; a < 4; ++a)
        #pragma unroll
        for (int b = 0; b < 4; ++b) acc[a][b] = (f32x4)0.f;

    const int r0  = t >> 2;
    const int ch0 = t & 3;

    for (int kb = 0; kb < DD; kb += 32) {
        __syncthreads();
        #pragma unroll
        for (int half = 0; half < 2; ++half) {
            const int row = r0 + half * 64;
            const int cs  = ch0 ^ ((row >> 2) & 3);
            cvt8(inp + (size_t)(5 * (i0 + row)) * DD + kb + ch0 * 8,
                 &AsHi[row][cs], &AsLo[row][cs]);
            cvt8(inp + (size_t)(c0 + row) * DD + kb + ch0 * 8,
                 &BsHi[row][cs], &BsLo[row][cs]);
        }
        __syncthreads();

        bf16x8 bh[4], bl[4];
        #pragma unroll
        for (int fc = 0; fc < 4; ++fc) {
            const int col = wc + fc * 16 + l15;
            const int cs  = l4 ^ ((col >> 2) & 3);
            bh[fc] = *(const bf16x8*)&BsHi[col][cs];
            bl[fc] = *(const bf16x8*)&BsLo[col][cs];
        }
        #pragma unroll
        for (int fr = 0; fr < 4; ++fr) {
            const int row = wr + fr * 16 + l15;
            const int cs  = l4 ^ ((row >> 2) & 3);
            bf16x8 ah = *(const bf16x8*)&AsHi[row][cs];
            bf16x8 al = *(const bf16x8*)&AsLo[row][cs];
            #pragma unroll
            for (int fc = 0; fc < 4; ++fc) {
                acc[fr][fc] = __builtin_amdgcn_mfma_f32_16x16x32_bf16(ah, bh[fc], acc[fr][fc], 0, 0, 0);
                acc[fr][fc] = __builtin_amdgcn_mfma_f32_16x16x32_bf16(ah, bl[fc], acc[fr][fc], 0, 0, 0);
                acc[fr][fc] = __builtin_amdgcn_mfma_f32_16x16x32_bf16(al, bh[fc], acc[fr][fc], 0, 0, 0);
            }
        }
    }

    #pragma unroll
    for (int fr = 0; fr < 4; ++fr) {
        #pragma unroll
        for (int reg = 0; reg < 4; ++reg) {
            const int i = i0 + wr + fr * 16 + l4 * 4 + reg;
            row_epilogue(i, c0, wc, l15,
                         acc[fr][0][reg], acc[fr][1][reg],
                         acc[fr][2][reg], acc[fr][3][reg],
                         posmin, negkey, msum, cntn);
        }
    }
}

// ============================================================================
// Kernel 3: finalize.
// ============================================================================
__global__ __launch_bounds__(1024) void fin_kernel(const float* __restrict__ pos,
        const unsigned* __restrict__ negkey, const double* __restrict__ msum,
        const unsigned* __restrict__ cntn, float* __restrict__ out)
{
    const int t = threadIdx.x;
    double lossAcc = 0.0;
    int pAcc = 0, nAcc = 0;
    for (int r = t; r < NB; r += 1024) {
        const float negmax = fdec(negkey[r]);
        const float thr = negmax + EPc;       // strict <
        float Mp = -INFINITY; int pc = 0;
        float pa[4]; bool pm[4];
        #pragma unroll
        for (int g = 0; g < 4; ++g) {
            const float p = pos[r * 4 + g];
            pa[g] = -ALPHAc * (p - LMDAc);
            pm[g] = (p < thr);
            if (pm[g]) { pc += 1; Mp = fmaxf(Mp, pa[g]); }
        }
        double lp = 0.0;
        if (pc > 0) {
            float sp = 0.f;
            #pragma unroll
            for (int g = 0; g < 4; ++g)
                if (pm[g]) sp += __expf(pa[g] - Mp);
            double a = (double)Mp + log((double)sp);
            lp = (a > 30.0 ? a : log1p(exp(a))) / (double)ALPHAc;
        }
        double ln = 0.0;
        double Dsum = msum[r];
        if (Dsum > 0.0) {
            double a = SHIFT + log(Dsum);
            ln = (a > 30.0 ? a : log1p(exp(a))) / (double)BETAc;
        }
        double contrib = lp + ln;
        if (!(contrib < 1e30)) contrib = 1e30;
        lossAcc += contrib;
        pAcc += pc;
        nAcc += (int)cntn[r];
    }
    __shared__ double sl[1024];
    __shared__ int    sp_[1024];
    __shared__ int    sn_[1024];
    sl[t] = lossAcc; sp_[t] = pAcc; sn_[t] = nAcc;
    __syncthreads();
    for (int s = 512; s > 0; s >>= 1) {
        if (t < s) { sl[t] += sl[t + s]; sp_[t] += sp_[t + s]; sn_[t] += sn_[t + s]; }
        __syncthreads();
    }
    if (t == 0) {
        double loss = sl[0] / 4096.0;
        if (!(loss < 1e30)) loss = 1e30;
        out[0] = (float)loss;
        out[1] = (float)sp_[0] / 16384.0f;
        out[2] = (float)sn_[0] / 83865600.0f;
    }
}

// ============================================================================
extern "C" void kernel_launch(void* const* d_in, const int* in_sizes, int n_in,
                              void* d_out, int out_size, void* d_ws, size_t ws_size,
                              hipStream_t stream)
{
    (void)in_sizes; (void)n_in; (void)out_size;
    const float* inp = (const float*)d_in[0];   // (20480, 512) f32; targets unused
    char* ws = (char*)d_ws;
    // ws layout (bytes):
    //   [0      , 65536 )  pos      : 4096*4 f32
    //   [65536  , 81920 )  posmin   : 4096 f32
    //   [81920  , 98304 )  negkey   : 4096 u32
    //   [98304  , 131072)  msum     : 4096 f64
    //   [131072 , 147456)  cntn     : 4096 u32
    //   [147456 , +21.0MB)  Hi bf16 [BB][DD]
    //   [ ...   , +21.0MB)  Lo bf16 [BB][DD]
    float*    pos    = (float*)   (ws);
    float*    posmin = (float*)   (ws + 65536);
    unsigned* negkey = (unsigned*)(ws + 81920);
    double*   msum   = (double*)  (ws + 98304);
    unsigned* cntn   = (unsigned*)(ws + 131072);
    u32*      hi     = (u32*)     (ws + 147456);
    u32*      lo     = (u32*)     (ws + 147456 + (size_t)BB * DD * 2);
    float*    out    = (float*)d_out;
    const size_t need = 147456 + (size_t)BB * DD * 4;   // 42.1 MB

    hipMemsetAsync(ws + 81920, 0, 65536, stream);
    hipLaunchKernelGGL(pos_kernel, dim3(NB / 4), dim3(256), 0, stream, inp, pos, posmin);

    if (ws_size >= need) {
        hipLaunchKernelGGL(split_kernel, dim3(BB * DD / (256 * 8)), dim3(256), 0, stream,
                           inp, hi, lo);
        hipLaunchKernelGGL(sim_mfma8, dim3((NB / 256) * (BB / 256)), dim3(512), 0, stream,
                           hi, lo, posmin, negkey, msum, cntn);
    } else {
        hipLaunchKernelGGL(sim_mfma, dim3((NB / 128) * (BB / 128)), dim3(256), 0, stream,
                           inp, posmin, negkey, msum, cntn);
    }
    hipLaunchKernelGGL(fin_kernel, dim3(1), dim3(1024), 0, stream, pos, negkey, msum, cntn, out);
}

// Round 15
// 471.257 us; speedup vs baseline: 1.1100x; 1.0929x over previous
//
#include <hip/hip_runtime.h>
#include <hip/hip_bf16.h>
#include <math.h>

// Problem constants (fixed by the reference)
#define NB    4096      // number of anchors  (B / GROUP)
#define BB    20480     // total rows of inputs = columns of sim
#define DD    512       // feature dim
#define EPc    0.1f
#define BETAc  10.0f
#define ALPHAc 2.0f
#define LMDAc  1.0f
// LSE shift: masked args BETA*(s-1) span ~[-700, 1400].
#define SHIFT  1400.0

typedef __attribute__((ext_vector_type(8))) short bf16x8;   // 8 bf16 (4 VGPRs)
typedef __attribute__((ext_vector_type(4))) float f32x4;    // MFMA accumulator
typedef unsigned int u32;

// global_load_lds, 16B per lane (used by the mid-tier fallback only).
#define GLOAD16(gp, lp) \
    __builtin_amdgcn_global_load_lds((const __attribute__((address_space(1))) u32*)(gp), \
                                     (__attribute__((address_space(3))) u32*)(lp), 16, 0, 0)

// ---- monotone float <-> uint key (for atomicMax on float incl. negatives) ----
__device__ __forceinline__ unsigned fenc(float x) {
    unsigned b = __float_as_uint(x);
    return (b & 0x80000000u) ? ~b : (b | 0x80000000u);
}
__device__ __forceinline__ float fdec(unsigned k) {
    unsigned b = (k & 0x80000000u) ? (k ^ 0x80000000u) : ~k;
    return __uint_as_float(b);
}

// ---- f32 pair -> packed bf16 hi / lo words ----
__device__ __forceinline__ void split2(float a, float b, u32* h, u32* l) {
    __hip_bfloat16 ha = __float2bfloat16(a);
    __hip_bfloat16 hb = __float2bfloat16(b);
    unsigned short ba, bb;
    __builtin_memcpy(&ba, &ha, 2); __builtin_memcpy(&bb, &hb, 2);
    float fa = __uint_as_float((u32)ba << 16);
    float fb = __uint_as_float((u32)bb << 16);
    __hip_bfloat16 la = __float2bfloat16(a - fa);
    __hip_bfloat16 lb = __float2bfloat16(b - fb);
    unsigned short ca, cb;
    __builtin_memcpy(&ca, &la, 2); __builtin_memcpy(&cb, &lb, 2);
    *h = (u32)ba | ((u32)bb << 16);
    *l = (u32)ca | ((u32)cb << 16);
}

// ---- 8 floats -> one packed bf16x8 word (hi OR lo part) ----
__device__ __forceinline__ uint4 cvt8_sel(const float* __restrict__ src, bool lo_part) {
    float4 x0 = *(const float4*)(src);
    float4 x1 = *(const float4*)(src + 4);
    float xs[8] = {x0.x, x0.y, x0.z, x0.w, x1.x, x1.y, x1.z, x1.w};
    u32 w[4];
    #pragma unroll
    for (int p = 0; p < 4; ++p) {
        u32 h, l;
        split2(xs[2*p], xs[2*p+1], &h, &l);
        w[p] = lo_part ? l : h;
    }
    return make_uint4(w[0], w[1], w[2], w[3]);
}

// ============================================================================
// Pack kernels: fragment-linear layouts over virtual K = 1536 (48 kc-chunks).
//   slot = (blk*48 + kc)*64 + lane ; 16 B per slot.
//   lane -> (row = blk*16 + (lane&15), k = (kc%16)*32 + (lane>>4)*8 .. +8)
//   A segments (kc/16): {hi, lo, hi}.  B segments: {hi, hi, lo}.
// ============================================================================
__global__ __launch_bounds__(256) void packA_kernel(const float* __restrict__ inp,
        u32* __restrict__ apk)
{
    const u32 slot = blockIdx.x * 256 + threadIdx.x;      // < 786432
    const u32 lane = slot & 63;
    const u32 rest = slot >> 6;
    const u32 kc   = rest % 48;
    const u32 ablk = rest / 48;
    const int  i    = ablk * 16 + (lane & 15);            // anchor index
    const int  k0   = (kc % 16) * 32 + (lane >> 4) * 8;
    const bool lo_p = ((kc / 16) == 1);
    uint4 v = cvt8_sel(inp + (size_t)(5 * i) * DD + k0, lo_p);
    *(uint4*)(apk + (size_t)slot * 4) = v;
}

__global__ __launch_bounds__(256) void packB_kernel(const float* __restrict__ inp,
        u32* __restrict__ bpk)
{
    const u32 slot = blockIdx.x * 256 + threadIdx.x;      // < 3932160
    const u32 lane = slot & 63;
    const u32 rest = slot >> 6;
    const u32 kc   = rest % 48;
    const u32 cblk = rest / 48;
    const int  r    = cblk * 16 + (lane & 15);            // input row / sim col
    const int  k0   = (kc % 16) * 32 + (lane >> 4) * 8;
    const bool lo_p = ((kc / 16) == 2);
    uint4 v = cvt8_sel(inp + (size_t)r * DD + k0, lo_p);
    *(uint4*)(bpk + (size_t)slot * 4) = v;
}

// ============================================================================
// Kernel 0 (mid-tier): split inputs into Hi/Lo bf16 arrays (row-major).
// ============================================================================
__global__ __launch_bounds__(256) void split_kernel(const float* __restrict__ inp,
        u32* __restrict__ hi, u32* __restrict__ lo)
{
    const size_t e = ((size_t)blockIdx.x * 256 + threadIdx.x) * 8;
    float4 x0 = *(const float4*)(inp + e);
    float4 x1 = *(const float4*)(inp + e + 4);
    u32 h[4], l[4];
    split2(x0.x, x0.y, &h[0], &l[0]);
    split2(x0.z, x0.w, &h[1], &l[1]);
    split2(x1.x, x1.y, &h[2], &l[2]);
    split2(x1.z, x1.w, &h[3], &l[3]);
    *(uint4*)(hi + e / 2) = make_uint4(h[0], h[1], h[2], h[3]);
    *(uint4*)(lo + e / 2) = make_uint4(l[0], l[1], l[2], l[3]);
}

// ============================================================================
// Kernel 1: pos[i][g-1] = f_i . inputs[5i+g] (exact f32); posmin[i] = min
// ============================================================================
__global__ __launch_bounds__(256) void pos_kernel(const float* __restrict__ inp,
        float* __restrict__ pos, float* __restrict__ posmin)
{
    const int wid  = threadIdx.x >> 6;
    const int lane = threadIdx.x & 63;
    const int i = blockIdx.x * 4 + wid;
    const float* f = inp + (size_t)(5 * i) * DD + lane * 8;
    float4 fa = *(const float4*)(f);
    float4 fb = *(const float4*)(f + 4);
    float pmin = INFINITY;
    #pragma unroll
    for (int g = 1; g < 5; ++g) {
        const float* x = inp + (size_t)(5 * i + g) * DD + lane * 8;
        float4 xa = *(const float4*)(x);
        float4 xb = *(const float4*)(x + 4);
        float s = fa.x*xa.x + fa.y*xa.y + fa.z*xa.z + fa.w*xa.w
                + fb.x*xb.x + fb.y*xb.y + fb.z*xb.z + fb.w*xb.w;
        #pragma unroll
        for (int m = 1; m < 64; m <<= 1) s += __shfl_xor(s, m, 64);
        if (lane == 0) pos[i * 4 + (g - 1)] = s;
        pmin = fminf(pmin, s);
    }
    if (lane == 0) posmin[i] = pmin;
}

// ============================================================================
// Per-row LSE/max/count fold + atomics for one accumulator row-register.
// ============================================================================
__device__ __forceinline__ void row_epilogue(int i, int c0, int wc, int l15,
        float s0, float s1, float s2, float s3,
        const float* __restrict__ posmin, unsigned* __restrict__ negkey,
        double* __restrict__ msum, unsigned* __restrict__ cntn)
{
    const float th = posmin[i] - EPc;     // strict >
    float vmax = -INFINITY;
    float lM   = -INFINITY;
    float lS   = 0.f;
    int   vcnt = 0;
    float sv[4] = {s0, s1, s2, s3};
    float args[4]; bool msk[4];
    #pragma unroll
    for (int fc = 0; fc < 4; ++fc) {
        const int c = c0 + wc + fc * 16 + l15;
        const float s = sv[fc];
        const bool nonown = ((c / 5) != i);
        msk[fc]  = nonown && (s > th);
        args[fc] = BETAc * (s - LMDAc);
        if (nonown)  vmax = fmaxf(vmax, s);
        if (msk[fc]) { vcnt += 1; lM = fmaxf(lM, args[fc]); }
    }
    #pragma unroll
    for (int fc = 0; fc < 4; ++fc)
        if (msk[fc]) lS += __expf(args[fc] - lM);
    #pragma unroll
    for (int m = 1; m < 16; m <<= 1) {
        vmax  = fmaxf(vmax, __shfl_xor(vmax, m, 64));
        vcnt += __shfl_xor(vcnt, m, 64);
        float oM = __shfl_xor(lM, m, 64);
        float oS = __shfl_xor(lS, m, 64);
        if (oS != 0.f) {
            if (lS == 0.f)      { lM = oM; lS = oS; }
            else if (lM >= oM)  { lS += oS * __expf(oM - lM); }
            else                { lS = oS + lS * __expf(lM - oM); lM = oM; }
        }
    }
    if (l15 == 0) {
        atomicMax(&negkey[i], fenc(vmax));
        atomicAdd(&cntn[i], (unsigned)vcnt);
        if (lS > 0.f) {
            double e = (double)lM - SHIFT;
            if (e > 690.0) e = 690.0;
            double Dv = exp(e) * (double)lS;
            if (!(Dv < 1e300)) Dv = 1e300;    // also catches nan
            atomicAdd(&msum[i], Dv);
        }
    }
}

// ============================================================================
// Kernel 2 (fast path): NO-LDS register-direct MFMA GEMM on fragment-packed
// operands. 128x128 block, 4 waves (64x64 each, 4x4 frags of 16x16x32).
// Per kc: 8 perfectly-coalesced 1KB global loads -> 16 MFMA. No barriers,
// no LDS, no staging; compiler pipelines register loads across #pragma
// unroll iterations; 3 waves/EU via launch_bounds (no spill, ~12 waves/CU).
// Block mapping: 4x4 block chunks (A+B panels ~3.2 MB, L2-resident) assigned
// round-robin to XCDs (grid 5120 = 8 XCD x 40 chunks x 16 blocks).
// ============================================================================
__global__ __launch_bounds__(256, 3) void sim_mfma9(const u32* __restrict__ apk,
        const u32* __restrict__ bpk, const float* __restrict__ posmin,
        unsigned* __restrict__ negkey, double* __restrict__ msum,
        unsigned* __restrict__ cntn)
{
    const int t    = threadIdx.x;
    const int lane = t & 63;
    const int w    = t >> 6;
    const int l15  = lane & 15;
    const int l4   = lane >> 4;

    // ---- chunked XCD-aware block mapping (bijective on 5120) ----
    const int bid   = blockIdx.x;
    const int xcd   = bid & 7;
    const int r_    = bid >> 3;            // [0,640)
    const int chunk = r_ >> 4;             // 40 chunks per XCD
    const int pos   = r_ & 15;             // 16 blocks per chunk (4x4)
    const int gc    = xcd * 40 + chunk;    // [0,320) global chunk
    const int bi    = (gc & 7) * 4 + (pos & 3);    // [0,32)
    const int bj    = (gc >> 3) * 4 + (pos >> 2);  // [0,160)
    const int i0    = bi * 128;
    const int c0    = bj * 128;
    const int wr    = (w >> 1) * 64;
    const int wc    = (w & 1) * 64;

    // fragment base pointers (u32 units); kc stride = 64 lanes * 4 u32 = 256
    const u32* pa[4];
    const u32* pb[4];
    #pragma unroll
    for (int f = 0; f < 4; ++f) {
        const int ablk = bi * 8 + (w >> 1) * 4 + f;      // row-block of 16
        const int cblk = bj * 8 + (w & 1) * 4 + f;       // col-block of 16
        pa[f] = apk + ((size_t)ablk * 48 * 64 + lane) * 4;
        pb[f] = bpk + ((size_t)cblk * 48 * 64 + lane) * 4;
    }

    f32x4 acc[4][4];
    #pragma unroll
    for (int a = 0; a < 4; ++a)
        #pragma unroll
        for (int b = 0; b < 4; ++b) acc[a][b] = (f32x4)0.f;

    #pragma unroll 2
    for (int kc = 0; kc < 48; ++kc) {
        bf16x8 av[4], bv[4];
        #pragma unroll
        for (int f = 0; f < 4; ++f) av[f] = *(const bf16x8*)(pa[f] + kc * 256);
        #pragma unroll
        for (int f = 0; f < 4; ++f) bv[f] = *(const bf16x8*)(pb[f] + kc * 256);
        #pragma unroll
        for (int fr = 0; fr < 4; ++fr)
            #pragma unroll
            for (int fc = 0; fc < 4; ++fc)
                acc[fr][fc] = __builtin_amdgcn_mfma_f32_16x16x32_bf16(
                    av[fr], bv[fc], acc[fr][fc], 0, 0, 0);
    }

    // ---- fused epilogue. C/D layout: col = lane&15, row = (lane>>4)*4 + reg
    #pragma unroll
    for (int fr = 0; fr < 4; ++fr) {
        #pragma unroll
        for (int reg = 0; reg < 4; ++reg) {
            const int i = i0 + wr + fr * 16 + l4 * 4 + reg;
            row_epilogue(i, c0, wc, l15,
                         acc[fr][0][reg], acc[fr][1][reg],
                         acc[fr][2][reg], acc[fr][3][reg],
                         posmin, negkey, msum, cntn);
        }
    }
}

// ============================================================================
// Kernel 2 (mid fallback, ws >= 42.1 MB): r11's LDS counted-vmcnt GEMM.
// ============================================================================
__global__ __launch_bounds__(256) void sim_mfma7(const u32* __restrict__ hi,
        const u32* __restrict__ lo, const float* __restrict__ posmin,
        unsigned* __restrict__ negkey, double* __restrict__ msum,
        unsigned* __restrict__ cntn)
{
    __shared__ u32 As0[2048], Bs0[2048];
    __shared__ u32 As1[2048], Bs1[2048];

    const int t    = threadIdx.x;
    const int bj   = blockIdx.x % (BB / 128);
    const int bi   = blockIdx.x / (BB / 128);
    const int i0   = bi * 128;
    const int c0   = bj * 128;
    const int lane = t & 63;
    const int w    = t >> 6;
    const int wr   = (w >> 1) * 64;
    const int wc   = (w & 1) * 64;
    const int l15  = lane & 15;
    const int l4   = lane >> 4;

    const int srow = w * 32 + (lane >> 2);
    const int sc   = (lane & 3) ^ ((srow >> 1) & 3);
    const size_t rbA0 = (size_t)(5 * (i0 + srow))      * 1024 + sc * 16;
    const size_t rbA1 = (size_t)(5 * (i0 + srow + 16)) * 1024 + sc * 16;
    const size_t rbB0 = (size_t)(c0 + srow)      * 1024 + sc * 16;
    const size_t rbB1 = (size_t)(c0 + srow + 16) * 1024 + sc * 16;
    const int dL0 = (w * 32) * 16;
    const int dL1 = (w * 32 + 16) * 16;

#define STAGE(AS, BS, s) do {                                            \
    const int p_ = (s) >> 4;                                             \
    const size_t kk_ = (size_t)((s) & 15) * 64;                          \
    const char* bA_ = (const char*)(p_ == 1 ? lo : hi);                  \
    const char* bB_ = (const char*)(p_ == 2 ? lo : hi);                  \
    GLOAD16(bA_ + rbA0 + kk_, (AS) + dL0);                               \
    GLOAD16(bA_ + rbA1 + kk_, (AS) + dL1);                               \
    GLOAD16(bB_ + rbB0 + kk_, (BS) + dL0);                               \
    GLOAD16(bB_ + rbB1 + kk_, (BS) + dL1);                               \
} while (0)

    f32x4 acc[4][4];
    #pragma unroll
    for (int a = 0; a < 4; ++a)
        #pragma unroll
        for (int b = 0; b < 4; ++b) acc[a][b] = (f32x4)0.f;

    int aoff[4], boff[4];
    #pragma unroll
    for (int f = 0; f < 4; ++f) {
        const int row = wr + f * 16 + l15;
        const int col = wc + f * 16 + l15;
        aoff[f] = row * 64 + ((l4 ^ ((row >> 1) & 3)) * 16);
        boff[f] = col * 64 + ((l4 ^ ((col >> 1) & 3)) * 16);
    }

#define COMPUTE(AS, BS) do {                                             \
    bf16x8 bv[4];                                                        \
    _Pragma("unroll")                                                    \
    for (int fc = 0; fc < 4; ++fc)                                       \
        bv[fc] = *(const bf16x8*)((const char*)(BS) + boff[fc]);         \
    _Pragma("unroll")                                                    \
    for (int fr = 0; fr < 4; ++fr) {                                     \
        bf16x8 av = *(const bf16x8*)((const char*)(AS) + aoff[fr]);      \
        _Pragma("unroll")                                                \
        for (int fc = 0; fc < 4; ++fc)                                   \
            acc[fr][fc] = __builtin_amdgcn_mfma_f32_16x16x32_bf16(av, bv[fc], acc[fr][fc], 0, 0, 0); \
    }                                                                    \
} while (0)

#define VMCNT4  asm volatile("s_waitcnt vmcnt(4)" ::: "memory")
#define VMCNT0  asm volatile("s_waitcnt vmcnt(0)" ::: "memory")
#define MFENCE  asm volatile("" ::: "memory")
#define BARRIER __builtin_amdgcn_s_barrier()

    STAGE(As0, Bs0, 0);
    STAGE(As1, Bs1, 1);
    for (int it = 0; it < 23; ++it) {
        VMCNT4; BARRIER; MFENCE;
        COMPUTE(As0, Bs0);
        BARRIER; MFENCE;
        STAGE(As0, Bs0, 2 * it + 2);
        VMCNT4; BARRIER; MFENCE;
        COMPUTE(As1, Bs1);
        BARRIER; MFENCE;
        STAGE(As1, Bs1, 2 * it + 3);
    }
    VMCNT4; BARRIER; MFENCE;
    COMPUTE(As0, Bs0);
    VMCNT0; BARRIER; MFENCE;
    COMPUTE(As1, Bs1);

#undef STAGE
#undef COMPUTE
#undef VMCNT4
#undef VMCNT0
#undef MFENCE
#undef BARRIER

    #pragma unroll
    for (int fr = 0; fr < 4; ++fr) {
        #pragma unroll
        for (int reg = 0; reg < 4; ++reg) {
            const int i = i0 + wr + fr * 16 + l4 * 4 + reg;
            row_epilogue(i, c0, wc, l15,
                         acc[fr][0][reg], acc[fr][1][reg],
                         acc[fr][2][reg], acc[fr][3][reg],
                         posmin, negkey, msum, cntn);
        }
    }
}

// ============================================================================
// Kernel 2 (low fallback, tiny ws): in-kernel cvt, known-good from round 4.
// ============================================================================
__device__ __forceinline__ void cvt8(const float* __restrict__ src,
                                     uint4* __restrict__ dhi, uint4* __restrict__ dlo)
{
    float4 x0 = *(const float4*)(src);
    float4 x1 = *(const float4*)(src + 4);
    float xs[8] = {x0.x, x0.y, x0.z, x0.w, x1.x, x1.y, x1.z, x1.w};
    u32 h[4], l[4];
    #pragma unroll
    for (int p = 0; p < 4; ++p) split2(xs[2*p], xs[2*p+1], &h[p], &l[p]);
    *dhi = make_uint4(h[0], h[1], h[2], h[3]);
    *dlo = make_uint4(l[0], l[1], l[2], l[3]);
}

__global__ __launch_bounds__(256) void sim_mfma(const float* __restrict__ inp,
        const float* __restrict__ posmin, unsigned* __restrict__ negkey,
        double* __restrict__ msum, unsigned* __restrict__ cntn)
{
    __shared__ uint4 AsHi[128][4];
    __shared__ uint4 AsLo[128][4];
    __shared__ uint4 BsHi[128][4];
    __shared__ uint4 BsLo[128][4];

    const int t    = threadIdx.x;
    const int bj   = blockIdx.x % (BB / 128);
    const int bi   = blockIdx.x / (BB / 128);
    const int i0   = bi * 128;
    const int c0   = bj * 128;
    const int lane = t & 63;
    const int w    = t >> 6;
    const int wr   = (w >> 1) * 64;
    const int wc   = (w & 1) * 64;
    const int l15  = lane & 15;
    const int l4   = lane >> 4;

    f32x4 acc[4][4];
    #pragma unroll
    for (int a = 0; a < 4; ++a)
        #pragma unroll
        for (int b = 0; b < 4; ++b) acc[a][b] = (f32x4)0.f;

    const int r0  = t >> 2;
    const int ch0 = t & 3;

    for (int kb = 0; kb < DD; kb += 32) {
        __syncthreads();
        #pragma unroll
        for (int half = 0; half < 2; ++half) {
            const int row = r0 + half * 64;
            const int cs  = ch0 ^ ((row >> 2) & 3);
            cvt8(inp + (size_t)(5 * (i0 + row)) * DD + kb + ch0 * 8,
                 &AsHi[row][cs], &AsLo[row][cs]);
            cvt8(inp + (size_t)(c0 + row) * DD + kb + ch0 * 8,
                 &BsHi[row][cs], &BsLo[row][cs]);
        }
        __syncthreads();

        bf16x8 bh[4], bl[4];
        #pragma unroll
        for (int fc = 0; fc < 4; ++fc) {
            const int col = wc + fc * 16 + l15;
            const int cs  = l4 ^ ((col >> 2) & 3);
            bh[fc] = *(const bf16x8*)&BsHi[col][cs];
            bl[fc] = *(const bf16x8*)&BsLo[col][cs];
        }
        #pragma unroll
        for (int fr = 0; fr < 4; ++fr) {
            const int row = wr + fr * 16 + l15;
            const int cs  = l4 ^ ((row >> 2) & 3);
            bf16x8 ah = *(const bf16x8*)&AsHi[row][cs];
            bf16x8 al = *(const bf16x8*)&AsLo[row][cs];
            #pragma unroll
            for (int fc = 0; fc < 4; ++fc) {
                acc[fr][fc] = __builtin_amdgcn_mfma_f32_16x16x32_bf16(ah, bh[fc], acc[fr][fc], 0, 0, 0);
                acc[fr][fc] = __builtin_amdgcn_mfma_f32_16x16x32_bf16(ah, bl[fc], acc[fr][fc], 0, 0, 0);
                acc[fr][fc] = __builtin_amdgcn_mfma_f32_16x16x32_bf16(al, bh[fc], acc[fr][fc], 0, 0, 0);
            }
        }
    }

    #pragma unroll
    for (int fr = 0; fr < 4; ++fr) {
        #pragma unroll
        for (int reg = 0; reg < 4; ++reg) {
            const int i = i0 + wr + fr * 16 + l4 * 4 + reg;
            row_epilogue(i, c0, wc, l15,
                         acc[fr][0][reg], acc[fr][1][reg],
                         acc[fr][2][reg], acc[fr][3][reg],
                         posmin, negkey, msum, cntn);
        }
    }
}

// ============================================================================
// Kernel 3: finalize.
// ============================================================================
__global__ __launch_bounds__(1024) void fin_kernel(const float* __restrict__ pos,
        const unsigned* __restrict__ negkey, const double* __restrict__ msum,
        const unsigned* __restrict__ cntn, float* __restrict__ out)
{
    const int t = threadIdx.x;
    double lossAcc = 0.0;
    int pAcc = 0, nAcc = 0;
    for (int r = t; r < NB; r += 1024) {
        const float negmax = fdec(negkey[r]);
        const float thr = negmax + EPc;       // strict <
        float Mp = -INFINITY; int pc = 0;
        float pa[4]; bool pm[4];
        #pragma unroll
        for (int g = 0; g < 4; ++g) {
            const float p = pos[r * 4 + g];
            pa[g] = -ALPHAc * (p - LMDAc);
            pm[g] = (p < thr);
            if (pm[g]) { pc += 1; Mp = fmaxf(Mp, pa[g]); }
        }
        double lp = 0.0;
        if (pc > 0) {
            float sp = 0.f;
            #pragma unroll
            for (int g = 0; g < 4; ++g)
                if (pm[g]) sp += __expf(pa[g] - Mp);
            double a = (double)Mp + log((double)sp);
            lp = (a > 30.0 ? a : log1p(exp(a))) / (double)ALPHAc;
        }
        double ln = 0.0;
        double Dsum = msum[r];
        if (Dsum > 0.0) {
            double a = SHIFT + log(Dsum);
            ln = (a > 30.0 ? a : log1p(exp(a))) / (double)BETAc;
        }
        double contrib = lp + ln;
        if (!(contrib < 1e30)) contrib = 1e30;
        lossAcc += contrib;
        pAcc += pc;
        nAcc += (int)cntn[r];
    }
    __shared__ double sl[1024];
    __shared__ int    sp_[1024];
    __shared__ int    sn_[1024];
    sl[t] = lossAcc; sp_[t] = pAcc; sn_[t] = nAcc;
    __syncthreads();
    for (int s = 512; s > 0; s >>= 1) {
        if (t < s) { sl[t] += sl[t + s]; sp_[t] += sp_[t + s]; sn_[t] += sn_[t + s]; }
        __syncthreads();
    }
    if (t == 0) {
        double loss = sl[0] / 4096.0;
        if (!(loss < 1e30)) loss = 1e30;
        out[0] = (float)loss;
        out[1] = (float)sp_[0] / 16384.0f;
        out[2] = (float)sn_[0] / 83865600.0f;
    }
}

// ============================================================================
extern "C" void kernel_launch(void* const* d_in, const int* in_sizes, int n_in,
                              void* d_out, int out_size, void* d_ws, size_t ws_size,
                              hipStream_t stream)
{
    (void)in_sizes; (void)n_in; (void)out_size;
    const float* inp = (const float*)d_in[0];   // (20480, 512) f32; targets unused
    char* ws = (char*)d_ws;
    // ws layout (bytes):
    //   [0      , 65536 )  pos      : 4096*4 f32
    //   [65536  , 81920 )  posmin   : 4096 f32
    //   [81920  , 98304 )  negkey   : 4096 u32
    //   [98304  , 131072)  msum     : 4096 f64
    //   [131072 , 147456)  cntn     : 4096 u32
    //   pack path:  [147456, +12.58MB) Apk  ; then Bpk (+62.9MB)  = 75.6 MB
    //   mid path:   [147456, +21.0MB)  Hi   ; then Lo  (+21.0MB)  = 42.1 MB
    float*    pos    = (float*)   (ws);
    float*    posmin = (float*)   (ws + 65536);
    unsigned* negkey = (unsigned*)(ws + 81920);
    double*   msum   = (double*)  (ws + 98304);
    unsigned* cntn   = (unsigned*)(ws + 131072);
    float*    out    = (float*)d_out;

    u32* apk = (u32*)(ws + 147456);
    u32* bpk = (u32*)(ws + 147456 + (size_t)NB * 1536 * 2);
    u32* hi  = (u32*)(ws + 147456);
    u32* lo  = (u32*)(ws + 147456 + (size_t)BB * DD * 2);

    const size_t need_pack = 147456 + ((size_t)NB + BB) * 1536 * 2;  // 75.6 MB
    const size_t need_mid  = 147456 + (size_t)BB * DD * 4;           // 42.1 MB

    hipMemsetAsync(ws + 81920, 0, 65536, stream);
    hipLaunchKernelGGL(pos_kernel, dim3(NB / 4), dim3(256), 0, stream, inp, pos, posmin);

    if (ws_size >= need_pack) {
        hipLaunchKernelGGL(packA_kernel, dim3(NB / 16 * 48 * 64 / 256), dim3(256), 0, stream, inp, apk);
        hipLaunchKernelGGL(packB_kernel, dim3(BB / 16 * 48 * 64 / 256), dim3(256), 0, stream, inp, bpk);
        hipLaunchKernelGGL(sim_mfma9, dim3((NB / 128) * (BB / 128)), dim3(256), 0, stream,
                           apk, bpk, posmin, negkey, msum, cntn);
    } else if (ws_size >= need_mid) {
        hipLaunchKernelGGL(split_kernel, dim3(BB * DD / (256 * 8)), dim3(256), 0, stream,
                           inp, hi, lo);
        hipLaunchKernelGGL(sim_mfma7, dim3((NB / 128) * (BB / 128)), dim3(256), 0, stream,
                           hi, lo, posmin, negkey, msum, cntn);
    } else {
        hipLaunchKernelGGL(sim_mfma, dim3((NB / 128) * (BB / 128)), dim3(256), 0, stream,
                           inp, posmin, negkey, msum, cntn);
    }
    hipLaunchKernelGGL(fin_kernel, dim3(1), dim3(1024), 0, stream, pos, negkey, msum, cntn, out);
}

// Round 16
// 390.248 us; speedup vs baseline: 1.3404x; 1.2076x over previous
//
#include <hip/hip_runtime.h>
#include <hip/hip_bf16.h>
#include <math.h>

// Problem constants (fixed by the reference)
#define NB    4096      // number of anchors  (B / GROUP)
#define BB    20480     // total rows of inputs = columns of sim
#define DD    512       // feature dim
#define EPc    0.1f
#define BETAc  10.0f
#define ALPHAc 2.0f
#define LMDAc  1.0f
// LSE shift: masked args BETA*(s-1) span ~[-700, 1400].
#define SHIFT  1400.0

typedef __attribute__((ext_vector_type(8))) short bf16x8;   // 8 bf16 (4 VGPRs)
typedef __attribute__((ext_vector_type(4))) float f32x4;    // MFMA accumulator
typedef unsigned int u32;

// global_load_lds, 16B per lane (used by the mid-tier fallback only).
#define GLOAD16(gp, lp) \
    __builtin_amdgcn_global_load_lds((const __attribute__((address_space(1))) u32*)(gp), \
                                     (__attribute__((address_space(3))) u32*)(lp), 16, 0, 0)

// ---- monotone float <-> uint key (for atomicMax on float incl. negatives) ----
__device__ __forceinline__ unsigned fenc(float x) {
    unsigned b = __float_as_uint(x);
    return (b & 0x80000000u) ? ~b : (b | 0x80000000u);
}
__device__ __forceinline__ float fdec(unsigned k) {
    unsigned b = (k & 0x80000000u) ? (k ^ 0x80000000u) : ~k;
    return __uint_as_float(b);
}

// ---- f32 pair -> packed bf16 hi / lo words ----
__device__ __forceinline__ void split2(float a, float b, u32* h, u32* l) {
    __hip_bfloat16 ha = __float2bfloat16(a);
    __hip_bfloat16 hb = __float2bfloat16(b);
    unsigned short ba, bb;
    __builtin_memcpy(&ba, &ha, 2); __builtin_memcpy(&bb, &hb, 2);
    float fa = __uint_as_float((u32)ba << 16);
    float fb = __uint_as_float((u32)bb << 16);
    __hip_bfloat16 la = __float2bfloat16(a - fa);
    __hip_bfloat16 lb = __float2bfloat16(b - fb);
    unsigned short ca, cb;
    __builtin_memcpy(&ca, &la, 2); __builtin_memcpy(&cb, &lb, 2);
    *h = (u32)ba | ((u32)bb << 16);
    *l = (u32)ca | ((u32)cb << 16);
}

// ---- 8 floats -> one packed bf16x8 word (hi OR lo part) ----
__device__ __forceinline__ uint4 cvt8_sel(const float* __restrict__ src, bool lo_part) {
    float4 x0 = *(const float4*)(src);
    float4 x1 = *(const float4*)(src + 4);
    float xs[8] = {x0.x, x0.y, x0.z, x0.w, x1.x, x1.y, x1.z, x1.w};
    u32 w[4];
    #pragma unroll
    for (int p = 0; p < 4; ++p) {
        u32 h, l;
        split2(xs[2*p], xs[2*p+1], &h, &l);
        w[p] = lo_part ? l : h;
    }
    return make_uint4(w[0], w[1], w[2], w[3]);
}

// ============================================================================
// Pack kernels: fragment-linear layouts over virtual K = 1536 (48 kc-chunks).
//   slot = (blk*48 + kc)*64 + lane ; 16 B per slot.
//   lane -> (row = blk*16 + (lane&15), k = (kc%16)*32 + (lane>>4)*8 .. +8)
//   A segments (kc/16): {hi, lo, hi}.  B segments: {hi, hi, lo}.
// ============================================================================
__global__ __launch_bounds__(256) void packA_kernel(const float* __restrict__ inp,
        u32* __restrict__ apk)
{
    const u32 slot = blockIdx.x * 256 + threadIdx.x;      // < 786432
    const u32 lane = slot & 63;
    const u32 rest = slot >> 6;
    const u32 kc   = rest % 48;
    const u32 ablk = rest / 48;
    const int  i    = ablk * 16 + (lane & 15);            // anchor index
    const int  k0   = (kc % 16) * 32 + (lane >> 4) * 8;
    const bool lo_p = ((kc / 16) == 1);
    uint4 v = cvt8_sel(inp + (size_t)(5 * i) * DD + k0, lo_p);
    *(uint4*)(apk + (size_t)slot * 4) = v;
}

__global__ __launch_bounds__(256) void packB_kernel(const float* __restrict__ inp,
        u32* __restrict__ bpk)
{
    const u32 slot = blockIdx.x * 256 + threadIdx.x;      // < 3932160
    const u32 lane = slot & 63;
    const u32 rest = slot >> 6;
    const u32 kc   = rest % 48;
    const u32 cblk = rest / 48;
    const int  r    = cblk * 16 + (lane & 15);            // input row / sim col
    const int  k0   = (kc % 16) * 32 + (lane >> 4) * 8;
    const bool lo_p = ((kc / 16) == 2);
    uint4 v = cvt8_sel(inp + (size_t)r * DD + k0, lo_p);
    *(uint4*)(bpk + (size_t)slot * 4) = v;
}

// ============================================================================
// Kernel 0 (mid-tier): split inputs into Hi/Lo bf16 arrays (row-major).
// ============================================================================
__global__ __launch_bounds__(256) void split_kernel(const float* __restrict__ inp,
        u32* __restrict__ hi, u32* __restrict__ lo)
{
    const size_t e = ((size_t)blockIdx.x * 256 + threadIdx.x) * 8;
    float4 x0 = *(const float4*)(inp + e);
    float4 x1 = *(const float4*)(inp + e + 4);
    u32 h[4], l[4];
    split2(x0.x, x0.y, &h[0], &l[0]);
    split2(x0.z, x0.w, &h[1], &l[1]);
    split2(x1.x, x1.y, &h[2], &l[2]);
    split2(x1.z, x1.w, &h[3], &l[3]);
    *(uint4*)(hi + e / 2) = make_uint4(h[0], h[1], h[2], h[3]);
    *(uint4*)(lo + e / 2) = make_uint4(l[0], l[1], l[2], l[3]);
}

// ============================================================================
// Kernel 1: pos[i][g-1] = f_i . inputs[5i+g] (exact f32); posmin[i] = min
// ============================================================================
__global__ __launch_bounds__(256) void pos_kernel(const float* __restrict__ inp,
        float* __restrict__ pos, float* __restrict__ posmin)
{
    const int wid  = threadIdx.x >> 6;
    const int lane = threadIdx.x & 63;
    const int i = blockIdx.x * 4 + wid;
    const float* f = inp + (size_t)(5 * i) * DD + lane * 8;
    float4 fa = *(const float4*)(f);
    float4 fb = *(const float4*)(f + 4);
    float pmin = INFINITY;
    #pragma unroll
    for (int g = 1; g < 5; ++g) {
        const float* x = inp + (size_t)(5 * i + g) * DD + lane * 8;
        float4 xa = *(const float4*)(x);
        float4 xb = *(const float4*)(x + 4);
        float s = fa.x*xa.x + fa.y*xa.y + fa.z*xa.z + fa.w*xa.w
                + fb.x*xb.x + fb.y*xb.y + fb.z*xb.z + fb.w*xb.w;
        #pragma unroll
        for (int m = 1; m < 64; m <<= 1) s += __shfl_xor(s, m, 64);
        if (lane == 0) pos[i * 4 + (g - 1)] = s;
        pmin = fminf(pmin, s);
    }
    if (lane == 0) posmin[i] = pmin;
}

// ============================================================================
// Per-row LSE/max/count fold + atomics for one accumulator row-register.
// ============================================================================
__device__ __forceinline__ void row_epilogue(int i, int c0, int wc, int l15,
        float s0, float s1, float s2, float s3,
        const float* __restrict__ posmin, unsigned* __restrict__ negkey,
        double* __restrict__ msum, unsigned* __restrict__ cntn)
{
    const float th = posmin[i] - EPc;     // strict >
    float vmax = -INFINITY;
    float lM   = -INFINITY;
    float lS   = 0.f;
    int   vcnt = 0;
    float sv[4] = {s0, s1, s2, s3};
    float args[4]; bool msk[4];
    #pragma unroll
    for (int fc = 0; fc < 4; ++fc) {
        const int c = c0 + wc + fc * 16 + l15;
        const float s = sv[fc];
        const bool nonown = ((c / 5) != i);
        msk[fc]  = nonown && (s > th);
        args[fc] = BETAc * (s - LMDAc);
        if (nonown)  vmax = fmaxf(vmax, s);
        if (msk[fc]) { vcnt += 1; lM = fmaxf(lM, args[fc]); }
    }
    #pragma unroll
    for (int fc = 0; fc < 4; ++fc)
        if (msk[fc]) lS += __expf(args[fc] - lM);
    #pragma unroll
    for (int m = 1; m < 16; m <<= 1) {
        vmax  = fmaxf(vmax, __shfl_xor(vmax, m, 64));
        vcnt += __shfl_xor(vcnt, m, 64);
        float oM = __shfl_xor(lM, m, 64);
        float oS = __shfl_xor(lS, m, 64);
        if (oS != 0.f) {
            if (lS == 0.f)      { lM = oM; lS = oS; }
            else if (lM >= oM)  { lS += oS * __expf(oM - lM); }
            else                { lS = oS + lS * __expf(lM - oM); lM = oM; }
        }
    }
    if (l15 == 0) {
        atomicMax(&negkey[i], fenc(vmax));
        atomicAdd(&cntn[i], (unsigned)vcnt);
        if (lS > 0.f) {
            double e = (double)lM - SHIFT;
            if (e > 690.0) e = 690.0;
            double Dv = exp(e) * (double)lS;
            if (!(Dv < 1e300)) Dv = 1e300;    // also catches nan
            atomicAdd(&msum[i], Dv);
        }
    }
}

// ============================================================================
// Kernel 2 (fast path): NO-LDS register-direct MFMA GEMM on fragment-packed
// operands, with EXPLICIT register double-buffering (prefetch distance 1):
// loads for kc+1 are issued into the alternate register set BEFORE the MFMA
// cluster for kc, so the compiler's dataflow s_waitcnt waits only the
// consumed set (counted wait) while the next set's 8 loads stay in flight
// under the 16-MFMA cluster. No LDS, no barriers; waves fully independent.
// 128x128 block, 4 waves (64x64 each). setprio(1) around MFMA (independent-
// wave regime, T5). Block mapping: 4x4 chunks round-robin on XCDs.
// ============================================================================
__global__ __launch_bounds__(256, 3) void sim_mfma10(const u32* __restrict__ apk,
        const u32* __restrict__ bpk, const float* __restrict__ posmin,
        unsigned* __restrict__ negkey, double* __restrict__ msum,
        unsigned* __restrict__ cntn)
{
    const int t    = threadIdx.x;
    const int lane = t & 63;
    const int w    = t >> 6;
    const int l15  = lane & 15;
    const int l4   = lane >> 4;

    // ---- chunked XCD-aware block mapping (bijective on 5120) ----
    const int bid   = blockIdx.x;
    const int xcd   = bid & 7;
    const int r_    = bid >> 3;            // [0,640)
    const int chunk = r_ >> 4;             // 40 chunks per XCD
    const int pos   = r_ & 15;             // 16 blocks per chunk (4x4)
    const int gc    = xcd * 40 + chunk;    // [0,320) global chunk
    const int bi    = (gc & 7) * 4 + (pos & 3);    // [0,32)
    const int bj    = (gc >> 3) * 4 + (pos >> 2);  // [0,160)
    const int i0    = bi * 128;
    const int c0    = bj * 128;
    const int wr    = (w >> 1) * 64;
    const int wc    = (w & 1) * 64;

    // fragment base pointers (u32 units); kc stride = 64 lanes * 4 u32 = 256
    const u32* pa[4];
    const u32* pb[4];
    #pragma unroll
    for (int f = 0; f < 4; ++f) {
        const int ablk = bi * 8 + (w >> 1) * 4 + f;      // row-block of 16
        const int cblk = bj * 8 + (w & 1) * 4 + f;       // col-block of 16
        pa[f] = apk + ((size_t)ablk * 48 * 64 + lane) * 4;
        pb[f] = bpk + ((size_t)cblk * 48 * 64 + lane) * 4;
    }

    f32x4 acc[4][4];
    #pragma unroll
    for (int a = 0; a < 4; ++a)
        #pragma unroll
        for (int b = 0; b < 4; ++b) acc[a][b] = (f32x4)0.f;

#define LOADF(AV, BV, KC) do {                                           \
    _Pragma("unroll")                                                    \
    for (int f_ = 0; f_ < 4; ++f_) (AV)[f_] = *(const bf16x8*)(pa[f_] + (KC) * 256); \
    _Pragma("unroll")                                                    \
    for (int f_ = 0; f_ < 4; ++f_) (BV)[f_] = *(const bf16x8*)(pb[f_] + (KC) * 256); \
} while (0)

#define MMB(AV, BV) do {                                                 \
    __builtin_amdgcn_s_setprio(1);                                       \
    _Pragma("unroll")                                                    \
    for (int fr_ = 0; fr_ < 4; ++fr_)                                    \
        _Pragma("unroll")                                                \
        for (int fc_ = 0; fc_ < 4; ++fc_)                                \
            acc[fr_][fc_] = __builtin_amdgcn_mfma_f32_16x16x32_bf16(     \
                (AV)[fr_], (BV)[fc_], acc[fr_][fc_], 0, 0, 0);           \
    __builtin_amdgcn_s_setprio(0);                                       \
} while (0)

    bf16x8 a0[4], b0[4], a1[4], b1[4];
    LOADF(a0, b0, 0);                       // prologue
    #pragma unroll 1
    for (int kc = 0; kc < 48; kc += 2) {
        LOADF(a1, b1, kc + 1);              // prefetch next into alt set
        MMB(a0, b0);                        // compute current (waits only a0/b0)
        if (kc + 2 < 48) LOADF(a0, b0, kc + 2);
        MMB(a1, b1);
    }
#undef LOADF
#undef MMB

    // ---- fused epilogue. C/D layout: col = lane&15, row = (lane>>4)*4 + reg
    #pragma unroll
    for (int fr = 0; fr < 4; ++fr) {
        #pragma unroll
        for (int reg = 0; reg < 4; ++reg) {
            const int i = i0 + wr + fr * 16 + l4 * 4 + reg;
            row_epilogue(i, c0, wc, l15,
                         acc[fr][0][reg], acc[fr][1][reg],
                         acc[fr][2][reg], acc[fr][3][reg],
                         posmin, negkey, msum, cntn);
        }
    }
}

// ============================================================================
// Kernel 2 (mid fallback, ws >= 42.1 MB): r11's LDS counted-vmcnt GEMM.
// ============================================================================
__global__ __launch_bounds__(256) void sim_mfma7(const u32* __restrict__ hi,
        const u32* __restrict__ lo, const float* __restrict__ posmin,
        unsigned* __restrict__ negkey, double* __restrict__ msum,
        unsigned* __restrict__ cntn)
{
    __shared__ u32 As0[2048], Bs0[2048];
    __shared__ u32 As1[2048], Bs1[2048];

    const int t    = threadIdx.x;
    const int bj   = blockIdx.x % (BB / 128);
    const int bi   = blockIdx.x / (BB / 128);
    const int i0   = bi * 128;
    const int c0   = bj * 128;
    const int lane = t & 63;
    const int w    = t >> 6;
    const int wr   = (w >> 1) * 64;
    const int wc   = (w & 1) * 64;
    const int l15  = lane & 15;
    const int l4   = lane >> 4;

    const int srow = w * 32 + (lane >> 2);
    const int sc   = (lane & 3) ^ ((srow >> 1) & 3);
    const size_t rbA0 = (size_t)(5 * (i0 + srow))      * 1024 + sc * 16;
    const size_t rbA1 = (size_t)(5 * (i0 + srow + 16)) * 1024 + sc * 16;
    const size_t rbB0 = (size_t)(c0 + srow)      * 1024 + sc * 16;
    const size_t rbB1 = (size_t)(c0 + srow + 16) * 1024 + sc * 16;
    const int dL0 = (w * 32) * 16;
    const int dL1 = (w * 32 + 16) * 16;

#define STAGE(AS, BS, s) do {                                            \
    const int p_ = (s) >> 4;                                             \
    const size_t kk_ = (size_t)((s) & 15) * 64;                          \
    const char* bA_ = (const char*)(p_ == 1 ? lo : hi);                  \
    const char* bB_ = (const char*)(p_ == 2 ? lo : hi);                  \
    GLOAD16(bA_ + rbA0 + kk_, (AS) + dL0);                               \
    GLOAD16(bA_ + rbA1 + kk_, (AS) + dL1);                               \
    GLOAD16(bB_ + rbB0 + kk_, (BS) + dL0);                               \
    GLOAD16(bB_ + rbB1 + kk_, (BS) + dL1);                               \
} while (0)

    f32x4 acc[4][4];
    #pragma unroll
    for (int a = 0; a < 4; ++a)
        #pragma unroll
        for (int b = 0; b < 4; ++b) acc[a][b] = (f32x4)0.f;

    int aoff[4], boff[4];
    #pragma unroll
    for (int f = 0; f < 4; ++f) {
        const int row = wr + f * 16 + l15;
        const int col = wc + f * 16 + l15;
        aoff[f] = row * 64 + ((l4 ^ ((row >> 1) & 3)) * 16);
        boff[f] = col * 64 + ((l4 ^ ((col >> 1) & 3)) * 16);
    }

#define COMPUTE(AS, BS) do {                                             \
    bf16x8 bv[4];                                                        \
    _Pragma("unroll")                                                    \
    for (int fc = 0; fc < 4; ++fc)                                       \
        bv[fc] = *(const bf16x8*)((const char*)(BS) + boff[fc]);         \
    _Pragma("unroll")                                                    \
    for (int fr = 0; fr < 4; ++fr) {                                     \
        bf16x8 av = *(const bf16x8*)((const char*)(AS) + aoff[fr]);      \
        _Pragma("unroll")                                                \
        for (int fc = 0; fc < 4; ++fc)                                   \
            acc[fr][fc] = __builtin_amdgcn_mfma_f32_16x16x32_bf16(av, bv[fc], acc[fr][fc], 0, 0, 0); \
    }                                                                    \
} while (0)

#define VMCNT4  asm volatile("s_waitcnt vmcnt(4)" ::: "memory")
#define VMCNT0  asm volatile("s_waitcnt vmcnt(0)" ::: "memory")
#define MFENCE  asm volatile("" ::: "memory")
#define BARRIER __builtin_amdgcn_s_barrier()

    STAGE(As0, Bs0, 0);
    STAGE(As1, Bs1, 1);
    for (int it = 0; it < 23; ++it) {
        VMCNT4; BARRIER; MFENCE;
        COMPUTE(As0, Bs0);
        BARRIER; MFENCE;
        STAGE(As0, Bs0, 2 * it + 2);
        VMCNT4; BARRIER; MFENCE;
        COMPUTE(As1, Bs1);
        BARRIER; MFENCE;
        STAGE(As1, Bs1, 2 * it + 3);
    }
    VMCNT4; BARRIER; MFENCE;
    COMPUTE(As0, Bs0);
    VMCNT0; BARRIER; MFENCE;
    COMPUTE(As1, Bs1);

#undef STAGE
#undef COMPUTE
#undef VMCNT4
#undef VMCNT0
#undef MFENCE
#undef BARRIER

    #pragma unroll
    for (int fr = 0; fr < 4; ++fr) {
        #pragma unroll
        for (int reg = 0; reg < 4; ++reg) {
            const int i = i0 + wr + fr * 16 + l4 * 4 + reg;
            row_epilogue(i, c0, wc, l15,
                         acc[fr][0][reg], acc[fr][1][reg],
                         acc[fr][2][reg], acc[fr][3][reg],
                         posmin, negkey, msum, cntn);
        }
    }
}

// ============================================================================
// Kernel 2 (low fallback, tiny ws): in-kernel cvt, known-good from round 4.
// ============================================================================
__device__ __forceinline__ void cvt8(const float* __restrict__ src,
                                     uint4* __restrict__ dhi, uint4* __restrict__ dlo)
{
    float4 x0 = *(const float4*)(src);
    float4 x1 = *(const float4*)(src + 4);
    float xs[8] = {x0.x, x0.y, x0.z, x0.w, x1.x, x1.y, x1.z, x1.w};
    u32 h[4], l[4];
    #pragma unroll
    for (int p = 0; p < 4; ++p) split2(xs[2*p], xs[2*p+1], &h[p], &l[p]);
    *dhi = make_uint4(h[0], h[1], h[2], h[3]);
    *dlo = make_uint4(l[0], l[1], l[2], l[3]);
}

__global__ __launch_bounds__(256) void sim_mfma(const float* __restrict__ inp,
        const float* __restrict__ posmin, unsigned* __restrict__ negkey,
        double* __restrict__ msum, unsigned* __restrict__ cntn)
{
    __shared__ uint4 AsHi[128][4];
    __shared__ uint4 AsLo[128][4];
    __shared__ uint4 BsHi[128][4];
    __shared__ uint4 BsLo[128][4];

    const int t    = threadIdx.x;
    const int bj   = blockIdx.x % (BB / 128);
    const int bi   = blockIdx.x / (BB / 128);
    const int i0   = bi * 128;
    const int c0   = bj * 128;
    const int lane = t & 63;
    const int w    = t >> 6;
    const int wr   = (w >> 1) * 64;
    const int wc   = (w & 1) * 64;
    const int l15  = lane & 15;
    const int l4   = lane >> 4;

    f32x4 acc[4][4];
    #pragma unroll
    for (int a = 0; a < 4; ++a)
        #pragma unroll
        for (int b = 0; b < 4; ++b) acc[a][b] = (f32x4)0.f;

    const int r0  = t >> 2;
    const int ch0 = t & 3;

    for (int kb = 0; kb < DD; kb += 32) {
        __syncthreads();
        #pragma unroll
        for (int half = 0; half < 2; ++half) {
            const int row = r0 + half * 64;
            const int cs  = ch0 ^ ((row >> 2) & 3);
            cvt8(inp + (size_t)(5 * (i0 + row)) * DD + kb + ch0 * 8,
                 &AsHi[row][cs], &AsLo[row][cs]);
            cvt8(inp + (size_t)(c0 + row) * DD + kb + ch0 * 8,
                 &BsHi[row][cs], &BsLo[row][cs]);
        }
        __syncthreads();

        bf16x8 bh[4], bl[4];
        #pragma unroll
        for (int fc = 0; fc < 4; ++fc) {
            const int col = wc + fc * 16 + l15;
            const int cs  = l4 ^ ((col >> 2) & 3);
            bh[fc] = *(const bf16x8*)&BsHi[col][cs];
            bl[fc] = *(const bf16x8*)&BsLo[col][cs];
        }
        #pragma unroll
        for (int fr = 0; fr < 4; ++fr) {
            const int row = wr + fr * 16 + l15;
            const int cs  = l4 ^ ((row >> 2) & 3);
            bf16x8 ah = *(const bf16x8*)&AsHi[row][cs];
            bf16x8 al = *(const bf16x8*)&AsLo[row][cs];
            #pragma unroll
            for (int fc = 0; fc < 4; ++fc) {
                acc[fr][fc] = __builtin_amdgcn_mfma_f32_16x16x32_bf16(ah, bh[fc], acc[fr][fc], 0, 0, 0);
                acc[fr][fc] = __builtin_amdgcn_mfma_f32_16x16x32_bf16(ah, bl[fc], acc[fr][fc], 0, 0, 0);
                acc[fr][fc] = __builtin_amdgcn_mfma_f32_16x16x32_bf16(al, bh[fc], acc[fr][fc], 0, 0, 0);
            }
        }
    }

    #pragma unroll
    for (int fr = 0; fr < 4; ++fr) {
        #pragma unroll
        for (int reg = 0; reg < 4; ++reg) {
            const int i = i0 + wr + fr * 16 + l4 * 4 + reg;
            row_epilogue(i, c0, wc, l15,
                         acc[fr][0][reg], acc[fr][1][reg],
                         acc[fr][2][reg], acc[fr][3][reg],
                         posmin, negkey, msum, cntn);
        }
    }
}

// ============================================================================
// Kernel 3: finalize.
// ============================================================================
__global__ __launch_bounds__(1024) void fin_kernel(const float* __restrict__ pos,
        const unsigned* __restrict__ negkey, const double* __restrict__ msum,
        const unsigned* __restrict__ cntn, float* __restrict__ out)
{
    const int t = threadIdx.x;
    double lossAcc = 0.0;
    int pAcc = 0, nAcc = 0;
    for (int r = t; r < NB; r += 1024) {
        const float negmax = fdec(negkey[r]);
        const float thr = negmax + EPc;       // strict <
        float Mp = -INFINITY; int pc = 0;
        float pa[4]; bool pm[4];
        #pragma unroll
        for (int g = 0; g < 4; ++g) {
            const float p = pos[r * 4 + g];
            pa[g] = -ALPHAc * (p - LMDAc);
            pm[g] = (p < thr);
            if (pm[g]) { pc += 1; Mp = fmaxf(Mp, pa[g]); }
        }
        double lp = 0.0;
        if (pc > 0) {
            float sp = 0.f;
            #pragma unroll
            for (int g = 0; g < 4; ++g)
                if (pm[g]) sp += __expf(pa[g] - Mp);
            double a = (double)Mp + log((double)sp);
            lp = (a > 30.0 ? a : log1p(exp(a))) / (double)ALPHAc;
        }
        double ln = 0.0;
        double Dsum = msum[r];
        if (Dsum > 0.0) {
            double a = SHIFT + log(Dsum);
            ln = (a > 30.0 ? a : log1p(exp(a))) / (double)BETAc;
        }
        double contrib = lp + ln;
        if (!(contrib < 1e30)) contrib = 1e30;
        lossAcc += contrib;
        pAcc += pc;
        nAcc += (int)cntn[r];
    }
    __shared__ double sl[1024];
    __shared__ int    sp_[1024];
    __shared__ int    sn_[1024];
    sl[t] = lossAcc; sp_[t] = pAcc; sn_[t] = nAcc;
    __syncthreads();
    for (int s = 512; s > 0; s >>= 1) {
        if (t < s) { sl[t] += sl[t + s]; sp_[t] += sp_[t + s]; sn_[t] += sn_[t + s]; }
        __syncthreads();
    }
    if (t == 0) {
        double loss = sl[0] / 4096.0;
        if (!(loss < 1e30)) loss = 1e30;
        out[0] = (float)loss;
        out[1] = (float)sp_[0] / 16384.0f;
        out[2] = (float)sn_[0] / 83865600.0f;
    }
}

// ============================================================================
extern "C" void kernel_launch(void* const* d_in, const int* in_sizes, int n_in,
                              void* d_out, int out_size, void* d_ws, size_t ws_size,
                              hipStream_t stream)
{
    (void)in_sizes; (void)n_in; (void)out_size;
    const float* inp = (const float*)d_in[0];   // (20480, 512) f32; targets unused
    char* ws = (char*)d_ws;
    // ws layout (bytes):
    //   [0      , 65536 )  pos      : 4096*4 f32
    //   [65536  , 81920 )  posmin   : 4096 f32
    //   [81920  , 98304 )  negkey   : 4096 u32
    //   [98304  , 131072)  msum     : 4096 f64
    //   [131072 , 147456)  cntn     : 4096 u32
    //   pack path:  [147456, +12.58MB) Apk  ; then Bpk (+62.9MB)  = 75.6 MB
    //   mid path:   [147456, +21.0MB)  Hi   ; then Lo  (+21.0MB)  = 42.1 MB
    float*    pos    = (float*)   (ws);
    float*    posmin = (float*)   (ws + 65536);
    unsigned* negkey = (unsigned*)(ws + 81920);
    double*   msum   = (double*)  (ws + 98304);
    unsigned* cntn   = (unsigned*)(ws + 131072);
    float*    out    = (float*)d_out;

    u32* apk = (u32*)(ws + 147456);
    u32* bpk = (u32*)(ws + 147456 + (size_t)NB * 1536 * 2);
    u32* hi  = (u32*)(ws + 147456);
    u32* lo  = (u32*)(ws + 147456 + (size_t)BB * DD * 2);

    const size_t need_pack = 147456 + ((size_t)NB + BB) * 1536 * 2;  // 75.6 MB
    const size_t need_mid  = 147456 + (size_t)BB * DD * 4;           // 42.1 MB

    hipMemsetAsync(ws + 81920, 0, 65536, stream);
    hipLaunchKernelGGL(pos_kernel, dim3(NB / 4), dim3(256), 0, stream, inp, pos, posmin);

    if (ws_size >= need_pack) {
        hipLaunchKernelGGL(packA_kernel, dim3(NB / 16 * 48 * 64 / 256), dim3(256), 0, stream, inp, apk);
        hipLaunchKernelGGL(packB_kernel, dim3(BB / 16 * 48 * 64 / 256), dim3(256), 0, stream, inp, bpk);
        hipLaunchKernelGGL(sim_mfma10, dim3((NB / 128) * (BB / 128)), dim3(256), 0, stream,
                           apk, bpk, posmin, negkey, msum, cntn);
    } else if (ws_size >= need_mid) {
        hipLaunchKernelGGL(split_kernel, dim3(BB * DD / (256 * 8)), dim3(256), 0, stream,
                           inp, hi, lo);
        hipLaunchKernelGGL(sim_mfma7, dim3((NB / 128) * (BB / 128)), dim3(256), 0, stream,
                           hi, lo, posmin, negkey, msum, cntn);
    } else {
        hipLaunchKernelGGL(sim_mfma, dim3((NB / 128) * (BB / 128)), dim3(256), 0, stream,
                           inp, posmin, negkey, msum, cntn);
    }
    hipLaunchKernelGGL(fin_kernel, dim3(1), dim3(1024), 0, stream, pos, negkey, msum, cntn, out);
}